// Round 10
// baseline (121.539 us; speedup 1.0000x reference)
//
#include <hip/hip_runtime.h>
#include <math.h>

namespace {

constexpr int S = 1024;
constexpr int C = 512;
constexpr int NBATCH = 8;
constexpr int RTOT = NBATCH * S;  // 8192
constexpr int HEADS = 8;
constexpr int DH = 64;

typedef __attribute__((ext_vector_type(8))) short bf16x8;
typedef __attribute__((ext_vector_type(4))) float f32x4;
typedef __attribute__((ext_vector_type(16))) float f32x16;
typedef unsigned short u16;
typedef unsigned int u32;

__device__ __forceinline__ u16 f2bf(float x) {
  union { float f; u32 u; } v; v.f = x;
  u32 r = v.u + 0x7FFF + ((v.u >> 16) & 1);
  return (u16)(r >> 16);
}
__device__ __forceinline__ float bf2f(u16 b) {
  union { u32 u; float f; } v; v.u = (u32)b << 16; return v.f;
}
__device__ __forceinline__ u32 cvtpk(float a, float b) {  // lo=a, hi=b (RTNE)
  u32 r;
  asm("v_cvt_pk_bf16_f32 %0, %1, %2" : "=v"(r) : "v"(a), "v"(b));
  return r;
}
__device__ __forceinline__ void gl_lds16(const void* g, void* l) {
  auto gp = (const __attribute__((address_space(1))) u32*)g;
  auto lp = (__attribute__((address_space(3))) u32*)l;
  __builtin_amdgcn_global_load_lds(gp, lp, 16, 0, 0);
}

// ---------------- Fused LN: stats + apply + NCHW->(row,c) transpose + bf16 --
__global__ void ln_fused(const float* __restrict__ x, const float* __restrict__ qx,
                         const float* __restrict__ gx, const float* __restrict__ bx,
                         const float* __restrict__ gq, const float* __restrict__ bq,
                         u16* __restrict__ Xkv, u16* __restrict__ Xq) {
  __shared__ float Ssum[8][32], Ssq[8][32];
  __shared__ float mu_s[32], rs_s[32];
  __shared__ float T[32][65];
  int t = threadIdx.x;
  int si0 = blockIdx.x * 32;
  int isq = blockIdx.y & 1, n = blockIdx.y >> 1;
  const float* in = isq ? qx : x;
  const float* g  = isq ? gq : gx;
  const float* be = isq ? bq : bx;
  u16* out = isq ? Xq : Xkv;

  {
    int sl = t & 31, cg = t >> 5;
    const float* p = in + ((size_t)n * C + cg * 64) * S + si0 + sl;
    float s = 0.f, sq = 0.f;
#pragma unroll 8
    for (int c = 0; c < 64; c++) { float v = p[(size_t)c * S]; s += v; sq += v * v; }
    Ssum[cg][sl] = s; Ssq[cg][sl] = sq;
  }
  __syncthreads();
  if (t < 32) {
    float ss = 0.f, q2 = 0.f;
#pragma unroll
    for (int i = 0; i < 8; i++) { ss += Ssum[i][t]; q2 += Ssq[i][t]; }
    float m = ss * (1.0f / C);
    float var = q2 * (1.0f / C) - m * m;
    mu_s[t] = m; rs_s[t] = rsqrtf(var + 1e-5f);
  }
  __syncthreads();

  int si4 = (t & 7) * 4, cl = t >> 3;
  float4 mu4 = *(const float4*)&mu_s[si4];
  float4 rs4 = *(const float4*)&rs_s[si4];
  int wsl = t >> 3, wc8 = (t & 7) * 8;

  for (int c0 = 0; c0 < C; c0 += 64) {
#pragma unroll
    for (int i = 0; i < 2; i++) {
      int c = c0 + cl + i * 32;
      float4 v = *(const float4*)&in[((size_t)n * C + c) * S + si0 + si4];
      float gg = g[c], bb = be[c];
      T[si4 + 0][cl + i * 32] = (v.x - mu4.x) * rs4.x * gg + bb;
      T[si4 + 1][cl + i * 32] = (v.y - mu4.y) * rs4.y * gg + bb;
      T[si4 + 2][cl + i * 32] = (v.z - mu4.z) * rs4.z * gg + bb;
      T[si4 + 3][cl + i * 32] = (v.w - mu4.w) * rs4.w * gg + bb;
    }
    __syncthreads();
    u16 pk[8];
#pragma unroll
    for (int j = 0; j < 8; j++) pk[j] = f2bf(T[wsl][wc8 + j]);
    *(uint4*)&out[((size_t)(n * S + si0 + wsl)) * C + c0 + wc8] = *(const uint4*)pk;
    __syncthreads();
  }
}

// ---------------- Weight prep: W[k][col] -> Wt[col][k] bf16 (+split for proj)
__global__ void prep_w(const float* __restrict__ qw, const float* __restrict__ kvw,
                       const float* __restrict__ pw,
                       u16* __restrict__ Wtq, u16* __restrict__ Wtkv,
                       u16* __restrict__ Wph, u16* __restrict__ Wpl) {
  int z = blockIdx.z;
  int N = (z == 1) ? 1024 : 512;
  int col0 = blockIdx.y * 64;
  if (col0 >= N) return;
  int k0 = blockIdx.x * 64;
  const float* W = (z == 0) ? qw : (z == 1) ? kvw : pw;
  __shared__ float T[64][65];
  int t = threadIdx.x;
  int kl = t >> 4, c4 = (t & 15) * 4;
#pragma unroll
  for (int i = 0; i < 4; i++) {
    float4 v = *(const float4*)&W[(size_t)(k0 + kl + i * 16) * N + col0 + c4];
    T[kl + i * 16][c4 + 0] = v.x; T[kl + i * 16][c4 + 1] = v.y;
    T[kl + i * 16][c4 + 2] = v.z; T[kl + i * 16][c4 + 3] = v.w;
  }
  __syncthreads();
#pragma unroll
  for (int p = 0; p < 2; p++) {
    int cl = (t >> 3) + p * 32, k8 = (t & 7) * 8;
    u16 hi[8], lo[8];
#pragma unroll
    for (int j = 0; j < 8; j++) {
      float f = T[k8 + j][cl];
      u16 hv = f2bf(f);
      hi[j] = hv;
      lo[j] = f2bf(f - bf2f(hv));
    }
    size_t o = (size_t)(col0 + cl) * 512 + k0 + k8;
    if (z == 0) *(uint4*)&Wtq[o] = *(const uint4*)hi;
    else if (z == 1) *(uint4*)&Wtkv[o] = *(const uint4*)hi;
    else { *(uint4*)&Wph[o] = *(const uint4*)hi; *(uint4*)&Wpl[o] = *(const uint4*)lo; }
  }
}

// ---------------- MFMA GEMM: merged q+kv projection, 128x128 tile -----------
__global__ __launch_bounds__(256, 4) void gemm_qkv(
    const u16* __restrict__ Xq, const u16* __restrict__ Xkv,
    const u16* __restrict__ Wtq, const u16* __restrict__ Wtkv,
    const float* __restrict__ q_b, const float* __restrict__ kv_b,
    u16* __restrict__ Qb, u16* __restrict__ Kb, u16* __restrict__ Vt) {
  __shared__ __attribute__((aligned(16))) u16 As[128 * 64];
  __shared__ __attribute__((aligned(16))) u16 Bs[128 * 64];
  int t = threadIdx.x, wid = t >> 6, lane = t & 63, lr = lane & 15, lg = lane >> 4;
  int colb = blockIdx.x;
  const u16* A; const u16* Wt; const float* bias; int ch0;
  if (colb < 4) { A = Xq;  Wt = Wtq  + (size_t)colb * 128 * 512;       bias = q_b  + colb * 128;       ch0 = colb * 128; }
  else          { A = Xkv; Wt = Wtkv + (size_t)(colb - 4) * 128 * 512; bias = kv_b + (colb - 4) * 128; ch0 = 512 + (colb - 4) * 128; }
  int row0 = blockIdx.y * 128;
  int wr = wid >> 1, wc = wid & 1;
  f32x4 acc[4][4];
#pragma unroll
  for (int m = 0; m < 4; m++)
#pragma unroll
    for (int n = 0; n < 4; n++) acc[m][n] = (f32x4){0.f, 0.f, 0.f, 0.f};

  for (int k0 = 0; k0 < 512; k0 += 64) {
    __syncthreads();
#pragma unroll
    for (int it = 0; it < 4; it++) {
      int chunk = (wid * 4 + it) * 64 + lane;
      int r = chunk >> 3, sg = chunk & 7;
      gl_lds16(A + (size_t)(row0 + r) * 512 + k0 + ((sg ^ (r & 7)) * 8),
               (char*)As + (size_t)chunk * 16);
    }
#pragma unroll
    for (int it = 0; it < 4; it++) {
      int chunk = (wid * 4 + it) * 64 + lane;
      int r = chunk >> 3, sg = chunk & 7;
      gl_lds16(Wt + (size_t)r * 512 + k0 + ((sg ^ (r & 7)) * 8),
               (char*)Bs + (size_t)chunk * 16);
    }
    __syncthreads();
#pragma unroll
    for (int kk = 0; kk < 2; kk++) {
      bf16x8 bfr[4];
#pragma unroll
      for (int n = 0; n < 4; n++) {
        int col = wc * 64 + n * 16 + lr;
        bfr[n] = *(const bf16x8*)((const char*)Bs + col * 128 + (((kk * 4 + lg) ^ (col & 7)) << 4));
      }
#pragma unroll
      for (int m = 0; m < 4; m++) {
        int row = wr * 64 + m * 16 + lr;
        bf16x8 af = *(const bf16x8*)((const char*)As + row * 128 + (((kk * 4 + lg) ^ (row & 7)) << 4));
#pragma unroll
        for (int n = 0; n < 4; n++)
          acc[m][n] = __builtin_amdgcn_mfma_f32_16x16x32_bf16(af, bfr[n], acc[m][n], 0, 0, 0);
      }
    }
  }
#pragma unroll
  for (int m = 0; m < 4; m++)
#pragma unroll
    for (int n = 0; n < 4; n++) {
      int colg = wc * 64 + n * 16 + lr;
      int ch = ch0 + colg;
      int h = ch / 192, role = (ch >> 6) % 3, d = ch & 63;
      float bs = bias[colg];
      float qsc = (role == 0) ? 0.18033688f : 1.0f;  // 0.125 * log2(e)
      int growb = row0 + wr * 64 + m * 16 + lg * 4;
      int nn = growb >> 10, ssi0 = growb & (S - 1);
      size_t nh = (size_t)(nn * HEADS + h);
      if (role == 2) {
        u16 pk[4];
#pragma unroll
        for (int r = 0; r < 4; r++) pk[r] = f2bf(acc[m][n][r] + bs);
        *(uint2*)&Vt[(nh * DH + d) * S + ssi0] = *(const uint2*)pk;
      } else {
        u16* dst = (role == 0) ? Qb : Kb;
#pragma unroll
        for (int r = 0; r < 4; r++)
          dst[(nh * S + ssi0 + r) * DH + d] = f2bf((acc[m][n][r] + bs) * qsc);
      }
    }
}

// ---------------- MFMA GEMM: proj (Obf bf16 -> out NCHW), W split hi+lo -----
__global__ __launch_bounds__(256) void gemm_proj(
    const u16* __restrict__ Aob, const u16* __restrict__ Wh, const u16* __restrict__ Wl,
    const float* __restrict__ bias, float* __restrict__ out) {
  __shared__ __attribute__((aligned(16))) u16 As[128 * 64];
  __shared__ __attribute__((aligned(16))) u16 Bh[64 * 64];
  __shared__ __attribute__((aligned(16))) u16 Bl[64 * 64];
  int t = threadIdx.x, wid = t >> 6, lane = t & 63, lr = lane & 15, lg = lane >> 4;
  int ch0 = blockIdx.x * 64, row0 = blockIdx.y * 128;
  int wc = wid & 1, wr = wid >> 1;
  f32x4 acc[2][4];
#pragma unroll
  for (int m = 0; m < 2; m++)
#pragma unroll
    for (int n = 0; n < 4; n++) acc[m][n] = (f32x4){0.f, 0.f, 0.f, 0.f};

  for (int k0 = 0; k0 < 512; k0 += 64) {
    __syncthreads();
#pragma unroll
    for (int it = 0; it < 4; it++) {
      int idx = (wid * 4 + it) * 64 + lane;
      int r = idx >> 3, sg = idx & 7;
      gl_lds16(Aob + (size_t)(row0 + r) * 512 + k0 + ((sg ^ (r & 7)) * 8),
               (char*)As + (wid * 4 + it) * 1024);
    }
#pragma unroll
    for (int it = 0; it < 2; it++) {
      int idx = (wid * 2 + it) * 64 + lane;
      int r = idx >> 3, sg = idx & 7;
      size_t go = (size_t)(ch0 + r) * 512 + k0 + ((sg ^ (r & 7)) * 8);
      gl_lds16(Wh + go, (char*)Bh + (wid * 2 + it) * 1024);
      gl_lds16(Wl + go, (char*)Bl + (wid * 2 + it) * 1024);
    }
    __syncthreads();
#pragma unroll
    for (int kk = 0; kk < 2; kk++) {
      bf16x8 ar[4];
#pragma unroll
      for (int n = 0; n < 4; n++) {
        int row = wr * 64 + n * 16 + lr;
        ar[n] = *(const bf16x8*)((const char*)As + row * 128 + (((kk * 4 + lg) ^ (row & 7)) << 4));
      }
#pragma unroll
      for (int m = 0; m < 2; m++) {
        int ch = wc * 32 + m * 16 + lr;
        bf16x8 bh = *(const bf16x8*)((const char*)Bh + ch * 128 + (((kk * 4 + lg) ^ (ch & 7)) << 4));
        bf16x8 bl = *(const bf16x8*)((const char*)Bl + ch * 128 + (((kk * 4 + lg) ^ (ch & 7)) << 4));
#pragma unroll
        for (int n = 0; n < 4; n++) {
          acc[m][n] = __builtin_amdgcn_mfma_f32_16x16x32_bf16(bh, ar[n], acc[m][n], 0, 0, 0);
          acc[m][n] = __builtin_amdgcn_mfma_f32_16x16x32_bf16(bl, ar[n], acc[m][n], 0, 0, 0);
        }
      }
    }
  }
#pragma unroll
  for (int m = 0; m < 2; m++)
#pragma unroll
    for (int n = 0; n < 4; n++) {
      int rowg = row0 + wr * 64 + n * 16 + lr;
      int nn = rowg >> 10, ssi = rowg & (S - 1);
#pragma unroll
      for (int r = 0; r < 4; r++) {
        int ch = ch0 + wc * 32 + m * 16 + lg * 4 + r;
        out[((size_t)nn * C + ch) * S + ssi] = acc[m][n][r] + bias[ch];
      }
    }
}

// ---------------- 32x32 MFMA flash attention: K/V direct from L2 ------------
// No LDS staging, no barriers in the main loop (m169 pattern: K/V per head =
// 512 KB, L2-resident; 16 co-XCD blocks per nh share it).
// Block = 64 q-rows, 4 waves: wave (qg=w&1, kg=w>>1); kg takes keys
// kg*512+[0,512) in 32-key tiles. O/m/l merged across kg at the end via LDS.
// permlane32_swap semantics (HW-confirmed r7): vdst.hi-lanes <-> vsrc.lo-lanes.
__global__ __launch_bounds__(256, 4) void attn_kernel(
    const u16* __restrict__ Qbf, const u16* __restrict__ Kbf,
    const u16* __restrict__ Vtb, u16* __restrict__ Obf) {
  __shared__ float exO[2][32][64];   // [qg][reg][lane] 16 KB (merge only)
  __shared__ float exS[2][2][64];    // [qg][{m,l}][lane] 1 KB

  int tid = threadIdx.x;
  int wave = tid >> 6, lane = tid & 63;
  int lq = lane & 31, hi = lane >> 5;
  int qg = wave & 1, kg = wave >> 1;
  // XCD-chunked swizzle: 1024 blocks, 8 XCDs, 128/chunk; 16 blocks per nh
  int w = (blockIdx.x & 7) * 128 + (blockIdx.x >> 3);
  int qt = w & 15, nh = w >> 4;
  const u16* Qg = Qbf + (size_t)nh * S * DH;
  const u16* Kg = Kbf + (size_t)nh * S * DH + (size_t)(kg * 512) * DH;
  const u16* Vg = Vtb + (size_t)nh * DH * S + kg * 512;

  // Q fragments (B-operand): lane holds Q[qrow][ks*16 + hi*8 + 0..7]
  int qrow = qt * 64 + qg * 32 + lq;
  bf16x8 qf[4];
#pragma unroll
  for (int ks = 0; ks < 4; ks++)
    qf[ks] = *(const bf16x8*)(Qg + (size_t)qrow * DH + ks * 16 + hi * 8);

  f32x16 oa0 = {}, oa1 = {};
  float m_run = -1e30f, l_run = 0.f;   // per-lane (q), log2 domain

  for (int t = 0; t < 16; t++) {       // 32-key tiles within this wave's half
    const u16* Kt = Kg + (size_t)(t * 32) * DH;
    // K frags: lane (lq,hi) reads K[t*32+lq][ks*16+hi*8 ..+7] (16B global)
    bf16x8 kf0 = *(const bf16x8*)(Kt + (size_t)lq * DH + 0 * 16 + hi * 8);
    bf16x8 kf1 = *(const bf16x8*)(Kt + (size_t)lq * DH + 1 * 16 + hi * 8);
    bf16x8 kf2 = *(const bf16x8*)(Kt + (size_t)lq * DH + 2 * 16 + hi * 8);
    bf16x8 kf3 = *(const bf16x8*)(Kt + (size_t)lq * DH + 3 * 16 + hi * 8);
    // V frags (independent of softmax; issued early for latency hiding):
    // lane (lq,hi) reads Vt[d][t*32 + kk*16 + hi*8 ..+7], d = lq / 32+lq
    const u16* Vt0 = Vg + (size_t)lq * S + t * 32 + hi * 8;
    const u16* Vt1 = Vg + (size_t)(32 + lq) * S + t * 32 + hi * 8;
    bf16x8 vf00 = *(const bf16x8*)(Vt0);
    bf16x8 vf01 = *(const bf16x8*)(Vt0 + 16);
    bf16x8 vf10 = *(const bf16x8*)(Vt1);
    bf16x8 vf11 = *(const bf16x8*)(Vt1 + 16);

    // QK^T swapped: sc = K(32key x 64d) . Q(64d x 32q); lane col = q
    f32x16 sc = {};
    sc = __builtin_amdgcn_mfma_f32_32x32x16_bf16(kf0, qf[0], sc, 0, 0, 0);
    sc = __builtin_amdgcn_mfma_f32_32x32x16_bf16(kf1, qf[1], sc, 0, 0, 0);
    sc = __builtin_amdgcn_mfma_f32_32x32x16_bf16(kf2, qf[2], sc, 0, 0, 0);
    sc = __builtin_amdgcn_mfma_f32_32x32x16_bf16(kf3, qf[3], sc, 0, 0, 0);

    // tree max, then partner lane (hi halves share q)
    float mx[8];
#pragma unroll
    for (int r = 0; r < 8; r++) mx[r] = fmaxf(sc[2 * r], sc[2 * r + 1]);
#pragma unroll
    for (int r = 0; r < 4; r++) mx[r] = fmaxf(mx[r], mx[r + 4]);
    float pmax = fmaxf(fmaxf(mx[0], mx[1]), fmaxf(mx[2], mx[3]));
    pmax = fmaxf(pmax, __shfl_xor(pmax, 32));

    // defer-max: 11.5 log2-units = 8 nats
    if (!__all(pmax <= m_run + 11.5f)) {
      float mnew = fmaxf(m_run, pmax);
      float corr = __builtin_amdgcn_exp2f(m_run - mnew);
      m_run = mnew;
      l_run *= corr;
#pragma unroll
      for (int r = 0; r < 16; r++) { oa0[r] *= corr; oa1[r] *= corr; }
    }

    // exp2 (raw v_exp_f32) + tree sum
#pragma unroll
    for (int r = 0; r < 16; r++) sc[r] = __builtin_amdgcn_exp2f(sc[r] - m_run);
    {
      float s8[8];
#pragma unroll
      for (int r = 0; r < 8; r++) s8[r] = sc[2 * r] + sc[2 * r + 1];
#pragma unroll
      for (int r = 0; r < 4; r++) s8[r] += s8[r + 4];
      float psum = (s8[0] + s8[1]) + (s8[2] + s8[3]);
      psum += __shfl_xor(psum, 32);
      l_run += psum;
    }

    // pack P to bf16 pairs and exchange halves in-register
    u32 c[8];
    c[0] = cvtpk(sc[0],  sc[1]);  c[1] = cvtpk(sc[2],  sc[3]);
    c[2] = cvtpk(sc[4],  sc[5]);  c[3] = cvtpk(sc[6],  sc[7]);
    c[4] = cvtpk(sc[8],  sc[9]);  c[5] = cvtpk(sc[10], sc[11]);
    c[6] = cvtpk(sc[12], sc[13]); c[7] = cvtpk(sc[14], sc[15]);
    asm("v_permlane32_swap_b32 %0, %1" : "+v"(c[0]), "+v"(c[2]));
    asm("v_permlane32_swap_b32 %0, %1" : "+v"(c[1]), "+v"(c[3]));
    asm("v_permlane32_swap_b32 %0, %1" : "+v"(c[4]), "+v"(c[6]));
    asm("v_permlane32_swap_b32 %0, %1" : "+v"(c[5]), "+v"(c[7]));

    // PV swapped: O(64d x 32q) += Vt(d x 16k) . P(16k x 32q)
    {
      union { u32 u[4]; bf16x8 v; } pu;
      pu.u[0] = c[0]; pu.u[1] = c[1]; pu.u[2] = c[2]; pu.u[3] = c[3];
      oa0 = __builtin_amdgcn_mfma_f32_32x32x16_bf16(vf00, pu.v, oa0, 0, 0, 0);
      oa1 = __builtin_amdgcn_mfma_f32_32x32x16_bf16(vf10, pu.v, oa1, 0, 0, 0);
      pu.u[0] = c[4]; pu.u[1] = c[5]; pu.u[2] = c[6]; pu.u[3] = c[7];
      oa0 = __builtin_amdgcn_mfma_f32_32x32x16_bf16(vf01, pu.v, oa0, 0, 0, 0);
      oa1 = __builtin_amdgcn_mfma_f32_32x32x16_bf16(vf11, pu.v, oa1, 0, 0, 0);
    }
  }

  // merge kg=1 partials into kg=0 (layout [reg][lane] -> conflict-free)
  __syncthreads();
  if (kg) {
#pragma unroll
    for (int r = 0; r < 16; r++) {
      exO[qg][r][lane] = oa0[r];
      exO[qg][16 + r][lane] = oa1[r];
    }
    exS[qg][0][lane] = m_run;
    exS[qg][1][lane] = l_run;
  }
  __syncthreads();
  if (!kg) {
    float m2 = exS[qg][0][lane];
    float l2 = exS[qg][1][lane];
    float m = fmaxf(m_run, m2);
    float f0 = __builtin_amdgcn_exp2f(m_run - m), f2 = __builtin_amdgcn_exp2f(m2 - m);
    l_run = l_run * f0 + l2 * f2;
#pragma unroll
    for (int r = 0; r < 16; r++) {
      oa0[r] = oa0[r] * f0 + exO[qg][r][lane] * f2;
      oa1[r] = oa1[r] * f0 + exO[qg][16 + r][lane] * f2;
    }
    // epilogue: oaX[r] = O[q=qrow][d = X*32 + (r&3) + 8*(r>>2) + 4*hi], / l
    int n = nh >> 3, h = nh & 7;
    float lf = 1.0f / l_run;
    u16* orow = Obf + ((size_t)n * S + qrow) * C + h * DH;
#pragma unroll
    for (int rq = 0; rq < 4; rq++) {
      int d0 = rq * 8 + 4 * hi;
      uint2 w0, w1;
      w0.x = cvtpk(oa0[rq * 4 + 0] * lf, oa0[rq * 4 + 1] * lf);
      w0.y = cvtpk(oa0[rq * 4 + 2] * lf, oa0[rq * 4 + 3] * lf);
      w1.x = cvtpk(oa1[rq * 4 + 0] * lf, oa1[rq * 4 + 1] * lf);
      w1.y = cvtpk(oa1[rq * 4 + 2] * lf, oa1[rq * 4 + 3] * lf);
      *(uint2*)(orow + d0) = w0;
      *(uint2*)(orow + 32 + d0) = w1;
    }
  }
}

}  // namespace

extern "C" void kernel_launch(void* const* d_in, const int* in_sizes, int n_in,
                              void* d_out, int out_size, void* d_ws, size_t ws_size,
                              hipStream_t stream) {
  const float* x       = (const float*)d_in[0];
  const float* qx      = (const float*)d_in[1];
  const float* q_ln_g  = (const float*)d_in[2];
  const float* q_ln_b  = (const float*)d_in[3];
  const float* q_w     = (const float*)d_in[4];
  const float* q_b     = (const float*)d_in[5];
  const float* kv_ln_g = (const float*)d_in[6];
  const float* kv_ln_b = (const float*)d_in[7];
  const float* kv_w    = (const float*)d_in[8];
  const float* kv_b    = (const float*)d_in[9];
  const float* proj_w  = (const float*)d_in[10];
  const float* proj_b  = (const float*)d_in[11];
  float* out = (float*)d_out;

  u16* u = (u16*)d_ws;
  u16* Xkv  = u;                u += (size_t)RTOT * C;
  u16* Xq   = u;                u += (size_t)RTOT * C;
  u16* Wtq  = u;                u += (size_t)C * C;
  u16* Wtkv = u;                u += (size_t)2 * C * C;
  u16* Wph  = u;                u += (size_t)C * C;
  u16* Wpl  = u;                u += (size_t)C * C;
  u16* Qb   = u;                u += (size_t)NBATCH * HEADS * S * DH;
  u16* Kb   = u;                u += (size_t)NBATCH * HEADS * S * DH;
  u16* Vt   = u;                u += (size_t)NBATCH * HEADS * S * DH;
  u16* Obf  = u;

  hipLaunchKernelGGL(ln_fused, dim3(S / 32, 2 * NBATCH), dim3(256), 0, stream,
                     x, qx, kv_ln_g, kv_ln_b, q_ln_g, q_ln_b, Xkv, Xq);
  hipLaunchKernelGGL(prep_w, dim3(8, 16, 3), dim3(256), 0, stream,
                     q_w, kv_w, proj_w, Wtq, Wtkv, Wph, Wpl);
  hipLaunchKernelGGL(gemm_qkv, dim3(12, RTOT / 128), dim3(256), 0, stream,
                     Xq, Xkv, Wtq, Wtkv, q_b, kv_b, Qb, Kb, Vt);
  hipLaunchKernelGGL(attn_kernel, dim3(1024), dim3(256), 0, stream,
                     Qb, Kb, Vt, Obf);
  hipLaunchKernelGGL(gemm_proj, dim3(C / 64, RTOT / 128), dim3(256), 0, stream,
                     Obf, Wph, Wpl, proj_b, out);
}

// Round 11
// 88.113 us; speedup vs baseline: 1.3793x; 1.3793x over previous
//
#include <hip/hip_runtime.h>
#include <math.h>

namespace {

constexpr int S = 1024;
constexpr int C = 512;
constexpr int NBATCH = 8;
constexpr int RTOT = NBATCH * S;  // 8192
constexpr int HEADS = 8;
constexpr int DH = 64;

typedef __attribute__((ext_vector_type(8))) short bf16x8;
typedef __attribute__((ext_vector_type(4))) float f32x4;
typedef __attribute__((ext_vector_type(16))) float f32x16;
typedef unsigned short u16;
typedef unsigned int u32;

__device__ __forceinline__ u16 f2bf(float x) {
  union { float f; u32 u; } v; v.f = x;
  u32 r = v.u + 0x7FFF + ((v.u >> 16) & 1);
  return (u16)(r >> 16);
}
__device__ __forceinline__ float bf2f(u16 b) {
  union { u32 u; float f; } v; v.u = (u32)b << 16; return v.f;
}
__device__ __forceinline__ u32 cvtpk(float a, float b) {  // lo=a, hi=b (RTNE)
  u32 r;
  asm("v_cvt_pk_bf16_f32 %0, %1, %2" : "=v"(r) : "v"(a), "v"(b));
  return r;
}
__device__ __forceinline__ float fexp2(float x) {  // raw v_exp_f32 (2^x)
  float r;
  asm("v_exp_f32 %0, %1" : "=v"(r) : "v"(x));
  return r;
}
__device__ __forceinline__ void gl_lds16(const void* g, void* l) {
  auto gp = (const __attribute__((address_space(1))) u32*)g;
  auto lp = (__attribute__((address_space(3))) u32*)l;
  __builtin_amdgcn_global_load_lds(gp, lp, 16, 0, 0);
}

// ---------------- Fused LN: stats + apply + NCHW->(row,c) transpose + bf16 --
__global__ void ln_fused(const float* __restrict__ x, const float* __restrict__ qx,
                         const float* __restrict__ gx, const float* __restrict__ bx,
                         const float* __restrict__ gq, const float* __restrict__ bq,
                         u16* __restrict__ Xkv, u16* __restrict__ Xq) {
  __shared__ float Ssum[8][32], Ssq[8][32];
  __shared__ float mu_s[32], rs_s[32];
  __shared__ float T[32][65];
  int t = threadIdx.x;
  int si0 = blockIdx.x * 32;
  int isq = blockIdx.y & 1, n = blockIdx.y >> 1;
  const float* in = isq ? qx : x;
  const float* g  = isq ? gq : gx;
  const float* be = isq ? bq : bx;
  u16* out = isq ? Xq : Xkv;

  {
    int sl = t & 31, cg = t >> 5;
    const float* p = in + ((size_t)n * C + cg * 64) * S + si0 + sl;
    float s = 0.f, sq = 0.f;
#pragma unroll 8
    for (int c = 0; c < 64; c++) { float v = p[(size_t)c * S]; s += v; sq += v * v; }
    Ssum[cg][sl] = s; Ssq[cg][sl] = sq;
  }
  __syncthreads();
  if (t < 32) {
    float ss = 0.f, q2 = 0.f;
#pragma unroll
    for (int i = 0; i < 8; i++) { ss += Ssum[i][t]; q2 += Ssq[i][t]; }
    float m = ss * (1.0f / C);
    float var = q2 * (1.0f / C) - m * m;
    mu_s[t] = m; rs_s[t] = rsqrtf(var + 1e-5f);
  }
  __syncthreads();

  int si4 = (t & 7) * 4, cl = t >> 3;
  float4 mu4 = *(const float4*)&mu_s[si4];
  float4 rs4 = *(const float4*)&rs_s[si4];
  int wsl = t >> 3, wc8 = (t & 7) * 8;

  for (int c0 = 0; c0 < C; c0 += 64) {
#pragma unroll
    for (int i = 0; i < 2; i++) {
      int c = c0 + cl + i * 32;
      float4 v = *(const float4*)&in[((size_t)n * C + c) * S + si0 + si4];
      float gg = g[c], bb = be[c];
      T[si4 + 0][cl + i * 32] = (v.x - mu4.x) * rs4.x * gg + bb;
      T[si4 + 1][cl + i * 32] = (v.y - mu4.y) * rs4.y * gg + bb;
      T[si4 + 2][cl + i * 32] = (v.z - mu4.z) * rs4.z * gg + bb;
      T[si4 + 3][cl + i * 32] = (v.w - mu4.w) * rs4.w * gg + bb;
    }
    __syncthreads();
    u16 pk[8];
#pragma unroll
    for (int j = 0; j < 8; j++) pk[j] = f2bf(T[wsl][wc8 + j]);
    *(uint4*)&out[((size_t)(n * S + si0 + wsl)) * C + c0 + wc8] = *(const uint4*)pk;
    __syncthreads();
  }
}

// ---------------- Weight prep: W[k][col] -> Wt[col][k] bf16 -----------------
__global__ void prep_w(const float* __restrict__ qw, const float* __restrict__ kvw,
                       const float* __restrict__ pw,
                       u16* __restrict__ Wtq, u16* __restrict__ Wtkv,
                       u16* __restrict__ Wph) {
  int z = blockIdx.z;
  int N = (z == 1) ? 1024 : 512;
  int col0 = blockIdx.y * 64;
  if (col0 >= N) return;
  int k0 = blockIdx.x * 64;
  const float* W = (z == 0) ? qw : (z == 1) ? kvw : pw;
  __shared__ float T[64][65];
  int t = threadIdx.x;
  int kl = t >> 4, c4 = (t & 15) * 4;
#pragma unroll
  for (int i = 0; i < 4; i++) {
    float4 v = *(const float4*)&W[(size_t)(k0 + kl + i * 16) * N + col0 + c4];
    T[kl + i * 16][c4 + 0] = v.x; T[kl + i * 16][c4 + 1] = v.y;
    T[kl + i * 16][c4 + 2] = v.z; T[kl + i * 16][c4 + 3] = v.w;
  }
  __syncthreads();
#pragma unroll
  for (int p = 0; p < 2; p++) {
    int cl = (t >> 3) + p * 32, k8 = (t & 7) * 8;
    u16 hi[8];
#pragma unroll
    for (int j = 0; j < 8; j++) hi[j] = f2bf(T[k8 + j][cl]);
    size_t o = (size_t)(col0 + cl) * 512 + k0 + k8;
    if (z == 0) *(uint4*)&Wtq[o] = *(const uint4*)hi;
    else if (z == 1) *(uint4*)&Wtkv[o] = *(const uint4*)hi;
    else *(uint4*)&Wph[o] = *(const uint4*)hi;
  }
}

// ---------------- MFMA GEMM: merged q+kv projection, 128x128 tile -----------
__global__ __launch_bounds__(256, 4) void gemm_qkv(
    const u16* __restrict__ Xq, const u16* __restrict__ Xkv,
    const u16* __restrict__ Wtq, const u16* __restrict__ Wtkv,
    const float* __restrict__ q_b, const float* __restrict__ kv_b,
    u16* __restrict__ Qb, u16* __restrict__ Kb, u16* __restrict__ Vt) {
  __shared__ __attribute__((aligned(16))) u16 As[128 * 64];
  __shared__ __attribute__((aligned(16))) u16 Bs[128 * 64];
  int t = threadIdx.x, wid = t >> 6, lane = t & 63, lr = lane & 15, lg = lane >> 4;
  int colb = blockIdx.x;
  const u16* A; const u16* Wt; const float* bias; int ch0;
  if (colb < 4) { A = Xq;  Wt = Wtq  + (size_t)colb * 128 * 512;       bias = q_b  + colb * 128;       ch0 = colb * 128; }
  else          { A = Xkv; Wt = Wtkv + (size_t)(colb - 4) * 128 * 512; bias = kv_b + (colb - 4) * 128; ch0 = 512 + (colb - 4) * 128; }
  int row0 = blockIdx.y * 128;
  int wr = wid >> 1, wc = wid & 1;
  f32x4 acc[4][4];
#pragma unroll
  for (int m = 0; m < 4; m++)
#pragma unroll
    for (int n = 0; n < 4; n++) acc[m][n] = (f32x4){0.f, 0.f, 0.f, 0.f};

  for (int k0 = 0; k0 < 512; k0 += 64) {
    __syncthreads();
#pragma unroll
    for (int it = 0; it < 4; it++) {
      int chunk = (wid * 4 + it) * 64 + lane;
      int r = chunk >> 3, sg = chunk & 7;
      gl_lds16(A + (size_t)(row0 + r) * 512 + k0 + ((sg ^ (r & 7)) * 8),
               (char*)As + (size_t)chunk * 16);
    }
#pragma unroll
    for (int it = 0; it < 4; it++) {
      int chunk = (wid * 4 + it) * 64 + lane;
      int r = chunk >> 3, sg = chunk & 7;
      gl_lds16(Wt + (size_t)r * 512 + k0 + ((sg ^ (r & 7)) * 8),
               (char*)Bs + (size_t)chunk * 16);
    }
    __syncthreads();
#pragma unroll
    for (int kk = 0; kk < 2; kk++) {
      bf16x8 bfr[4];
#pragma unroll
      for (int n = 0; n < 4; n++) {
        int col = wc * 64 + n * 16 + lr;
        bfr[n] = *(const bf16x8*)((const char*)Bs + col * 128 + (((kk * 4 + lg) ^ (col & 7)) << 4));
      }
#pragma unroll
      for (int m = 0; m < 4; m++) {
        int row = wr * 64 + m * 16 + lr;
        bf16x8 af = *(const bf16x8*)((const char*)As + row * 128 + (((kk * 4 + lg) ^ (row & 7)) << 4));
#pragma unroll
        for (int n = 0; n < 4; n++)
          acc[m][n] = __builtin_amdgcn_mfma_f32_16x16x32_bf16(af, bfr[n], acc[m][n], 0, 0, 0);
      }
    }
  }
#pragma unroll
  for (int m = 0; m < 4; m++)
#pragma unroll
    for (int n = 0; n < 4; n++) {
      int colg = wc * 64 + n * 16 + lr;
      int ch = ch0 + colg;
      int h = ch / 192, role = (ch >> 6) % 3, d = ch & 63;
      float bs = bias[colg];
      float qsc = (role == 0) ? 0.18033688f : 1.0f;  // 0.125 * log2(e)
      int growb = row0 + wr * 64 + m * 16 + lg * 4;
      int nn = growb >> 10, ssi0 = growb & (S - 1);
      size_t nh = (size_t)(nn * HEADS + h);
      if (role == 2) {
        u16 pk[4];
#pragma unroll
        for (int r = 0; r < 4; r++) pk[r] = f2bf(acc[m][n][r] + bs);
        *(uint2*)&Vt[(nh * DH + d) * S + ssi0] = *(const uint2*)pk;
      } else {
        u16* dst = (role == 0) ? Qb : Kb;
#pragma unroll
        for (int r = 0; r < 4; r++)
          dst[(nh * S + ssi0 + r) * DH + d] = f2bf((acc[m][n][r] + bs) * qsc);
      }
    }
}

// ---------------- MFMA GEMM: proj (Obf bf16 -> out NCHW), single bf16 W -----
__global__ __launch_bounds__(256) void gemm_proj(
    const u16* __restrict__ Aob, const u16* __restrict__ Wh,
    const float* __restrict__ bias, float* __restrict__ out) {
  __shared__ __attribute__((aligned(16))) u16 As[128 * 64];
  __shared__ __attribute__((aligned(16))) u16 Bh[64 * 64];
  int t = threadIdx.x, wid = t >> 6, lane = t & 63, lr = lane & 15, lg = lane >> 4;
  int ch0 = blockIdx.x * 64, row0 = blockIdx.y * 128;
  int wc = wid & 1, wr = wid >> 1;
  f32x4 acc[2][4];
#pragma unroll
  for (int m = 0; m < 2; m++)
#pragma unroll
    for (int n = 0; n < 4; n++) acc[m][n] = (f32x4){0.f, 0.f, 0.f, 0.f};

  for (int k0 = 0; k0 < 512; k0 += 64) {
    __syncthreads();
#pragma unroll
    for (int it = 0; it < 4; it++) {
      int idx = (wid * 4 + it) * 64 + lane;
      int r = idx >> 3, sg = idx & 7;
      gl_lds16(Aob + (size_t)(row0 + r) * 512 + k0 + ((sg ^ (r & 7)) * 8),
               (char*)As + (wid * 4 + it) * 1024);
    }
#pragma unroll
    for (int it = 0; it < 2; it++) {
      int idx = (wid * 2 + it) * 64 + lane;
      int r = idx >> 3, sg = idx & 7;
      gl_lds16(Wh + (size_t)(ch0 + r) * 512 + k0 + ((sg ^ (r & 7)) * 8),
               (char*)Bh + (wid * 2 + it) * 1024);
    }
    __syncthreads();
#pragma unroll
    for (int kk = 0; kk < 2; kk++) {
      bf16x8 ar[4];
#pragma unroll
      for (int n = 0; n < 4; n++) {
        int row = wr * 64 + n * 16 + lr;
        ar[n] = *(const bf16x8*)((const char*)As + row * 128 + (((kk * 4 + lg) ^ (row & 7)) << 4));
      }
#pragma unroll
      for (int m = 0; m < 2; m++) {
        int ch = wc * 32 + m * 16 + lr;
        bf16x8 bh = *(const bf16x8*)((const char*)Bh + ch * 128 + (((kk * 4 + lg) ^ (ch & 7)) << 4));
#pragma unroll
        for (int n = 0; n < 4; n++)
          acc[m][n] = __builtin_amdgcn_mfma_f32_16x16x32_bf16(bh, ar[n], acc[m][n], 0, 0, 0);
      }
    }
  }
#pragma unroll
  for (int m = 0; m < 2; m++)
#pragma unroll
    for (int n = 0; n < 4; n++) {
      int rowg = row0 + wr * 64 + n * 16 + lr;
      int nn = rowg >> 10, ssi = rowg & (S - 1);
#pragma unroll
      for (int r = 0; r < 4; r++) {
        int ch = ch0 + wc * 32 + m * 16 + lg * 4 + r;
        out[((size_t)nn * C + ch) * S + ssi] = acc[m][n][r] + bias[ch];
      }
    }
}

// ---------------- 32x32 MFMA flash attention, KV-split, in-register P -------
// (r9 structure: LDS-staged K/V, double-buffered; raw v_exp_f32; V hoisted)
// Block = 64 q-rows, 4 waves: wave (qg=w&1, kg=w>>1) handles q qg*32+[0,32)
// x keys kg*32+[0,32) of each 64-key tile. O/m/l merged across kg at end.
// permlane32_swap semantics (HW-confirmed r7): vdst.hi-lanes <-> vsrc.lo-lanes.
constexpr int KVB = 64;

__global__ __launch_bounds__(256, 4) void attn_kernel(
    const u16* __restrict__ Qbf, const u16* __restrict__ Kbf,
    const u16* __restrict__ Vtb, u16* __restrict__ Obf) {
  __shared__ __attribute__((aligned(16))) u16 Ks[2][KVB * DH];   // [key][d] 8KB x2
  __shared__ __attribute__((aligned(16))) u16 Vs[2][DH * KVB];   // [d][key] 8KB x2

  int tid = threadIdx.x;
  int wave = tid >> 6, lane = tid & 63;
  int lq = lane & 31, hi = lane >> 5;
  int qg = wave & 1, kg = wave >> 1;
  // XCD-chunked swizzle: 1024 blocks, 8 XCDs, 128/chunk; 16 blocks per nh
  int w = (blockIdx.x & 7) * 128 + (blockIdx.x >> 3);
  int qt = w & 15, nh = w >> 4;
  const u16* Qg = Qbf + (size_t)nh * S * DH;
  const u16* Kg = Kbf + (size_t)nh * S * DH;
  const u16* Vg = Vtb + (size_t)nh * DH * S;

  // Q fragments (B-operand): lane holds Q[qrow][ks*16 + hi*8 + 0..7]
  int qrow = qt * 64 + qg * 32 + lq;
  bf16x8 qf[4];
#pragma unroll
  for (int ks = 0; ks < 4; ks++)
    qf[ks] = *(const bf16x8*)(Qg + (size_t)qrow * DH + ks * 16 + hi * 8);

  f32x16 oa0 = {}, oa1 = {};
  float m_run = -1e30f, l_run = 0.f;   // per-lane (q = lq), log2 domain

  int e0i = tid, e1i = tid + 256;
  int r0 = e0i >> 3, sg0 = e0i & 7, r1 = e1i >> 3, sg1 = e1i & 7;
  char* kd0 = (char*)&Ks[0][0] + (e0i & ~63) * 16;
  char* kd1 = (char*)&Ks[0][0] + (e1i & ~63) * 16;
  char* vd0 = (char*)&Vs[0][0] + (e0i & ~63) * 16;
  char* vd1 = (char*)&Vs[0][0] + (e1i & ~63) * 16;

#define STAGE(kb, b)                                                             \
  do {                                                                           \
    gl_lds16(Kg + (size_t)((kb) * KVB + r0) * 64 + ((sg0 ^ (r0 & 7)) * 8),       \
             kd0 + (b) * (KVB * DH * 2));                                        \
    gl_lds16(Kg + (size_t)((kb) * KVB + r1) * 64 + ((sg1 ^ (r1 & 7)) * 8),       \
             kd1 + (b) * (KVB * DH * 2));                                        \
    gl_lds16(Vg + (size_t)r0 * S + (kb) * KVB + ((sg0 ^ (r0 & 7)) * 8),          \
             vd0 + (b) * (KVB * DH * 2));                                        \
    gl_lds16(Vg + (size_t)r1 * S + (kb) * KVB + ((sg1 ^ (r1 & 7)) * 8),          \
             vd1 + (b) * (KVB * DH * 2));                                        \
  } while (0)

  STAGE(0, 0);

  for (int kb = 0; kb < S / KVB; kb++) {
    int cur = kb & 1;
    __syncthreads();
    if (kb + 1 < S / KVB) STAGE(kb + 1, cur ^ 1);

    const char* Kc = (const char*)&Ks[cur][0];
    const char* Vc = (const char*)&Vs[cur][0];

    // QK^T swapped: sc = K(32key x 64d) . Q(64d x 32q); keys kg*32+[0,32)
    f32x16 sc = {};
#pragma unroll
    for (int ks = 0; ks < 4; ks++) {
      int sg = ks * 2 + hi;
      bf16x8 kf = *(const bf16x8*)(Kc + (kg * 32 + lq) * 128 + ((sg ^ (lq & 7)) << 4));
      sc = __builtin_amdgcn_mfma_f32_32x32x16_bf16(kf, qf[ks], sc, 0, 0, 0);
    }

    // V frags hoisted (independent of softmax -> latency hides under VALU)
    bf16x8 vfr[2][2];
#pragma unroll
    for (int kk = 0; kk < 2; kk++) {
      int sg = kg * 4 + kk * 2 + hi;
      vfr[kk][0] = *(const bf16x8*)(Vc + lq * 128 + ((sg ^ (lq & 7)) << 4));
      vfr[kk][1] = *(const bf16x8*)(Vc + (32 + lq) * 128 + ((sg ^ (lq & 7)) << 4));
    }

    // tree max over 16 regs, then partner lane (q shared by hi halves)
    float mx[8];
#pragma unroll
    for (int r = 0; r < 8; r++) mx[r] = fmaxf(sc[2 * r], sc[2 * r + 1]);
#pragma unroll
    for (int r = 0; r < 4; r++) mx[r] = fmaxf(mx[r], mx[r + 4]);
    float pmax = fmaxf(fmaxf(mx[0], mx[1]), fmaxf(mx[2], mx[3]));
    pmax = fmaxf(pmax, __shfl_xor(pmax, 32));

    // defer-max: 11.5 log2-units = 8 nats
    if (!__all(pmax <= m_run + 11.5f)) {
      float mnew = fmaxf(m_run, pmax);
      float corr = fexp2(m_run - mnew);
      m_run = mnew;
      l_run *= corr;
#pragma unroll
      for (int r = 0; r < 16; r++) { oa0[r] *= corr; oa1[r] *= corr; }
    }

    // exp2 (raw v_exp_f32, in place) + tree sum
#pragma unroll
    for (int r = 0; r < 16; r++) sc[r] = fexp2(sc[r] - m_run);
    {
      float s8[8];
#pragma unroll
      for (int r = 0; r < 8; r++) s8[r] = sc[2 * r] + sc[2 * r + 1];
#pragma unroll
      for (int r = 0; r < 4; r++) s8[r] += s8[r + 4];
      float psum = (s8[0] + s8[1]) + (s8[2] + s8[3]);
      psum += __shfl_xor(psum, 32);
      l_run += psum;
    }

    // pack P to bf16 pairs and exchange halves in-register
    u32 c[8];
    c[0] = cvtpk(sc[0],  sc[1]);  c[1] = cvtpk(sc[2],  sc[3]);
    c[2] = cvtpk(sc[4],  sc[5]);  c[3] = cvtpk(sc[6],  sc[7]);
    c[4] = cvtpk(sc[8],  sc[9]);  c[5] = cvtpk(sc[10], sc[11]);
    c[6] = cvtpk(sc[12], sc[13]); c[7] = cvtpk(sc[14], sc[15]);
    asm("v_permlane32_swap_b32 %0, %1" : "+v"(c[0]), "+v"(c[2]));
    asm("v_permlane32_swap_b32 %0, %1" : "+v"(c[1]), "+v"(c[3]));
    asm("v_permlane32_swap_b32 %0, %1" : "+v"(c[4]), "+v"(c[6]));
    asm("v_permlane32_swap_b32 %0, %1" : "+v"(c[5]), "+v"(c[7]));

    // PV swapped: O(64d x 32q) += Vt(d x 16k) . P(16k x 32q); keys kg*32+kk*16
#pragma unroll
    for (int kk = 0; kk < 2; kk++) {
      union { u32 u[4]; bf16x8 v; } pu;
      pu.u[0] = c[kk * 4 + 0]; pu.u[1] = c[kk * 4 + 1];
      pu.u[2] = c[kk * 4 + 2]; pu.u[3] = c[kk * 4 + 3];
      oa0 = __builtin_amdgcn_mfma_f32_32x32x16_bf16(vfr[kk][0], pu.v, oa0, 0, 0, 0);
      oa1 = __builtin_amdgcn_mfma_f32_32x32x16_bf16(vfr[kk][1], pu.v, oa1, 0, 0, 0);
    }
  }
#undef STAGE

  // merge kg=1 partials into kg=0 (layout [reg][lane] -> conflict-free)
  __syncthreads();
  float* exO = (float*)&Ks[0][0];   // 2 slots x 32 regs x 64 lanes = 16KB
  float* exS = (float*)&Vs[0][0];
  if (kg) {
    float* o = exO + qg * 2048;
#pragma unroll
    for (int r = 0; r < 16; r++) {
      o[r * 64 + lane] = oa0[r];
      o[(16 + r) * 64 + lane] = oa1[r];
    }
    exS[qg * 128 + lane] = m_run;
    exS[qg * 128 + 64 + lane] = l_run;
  }
  __syncthreads();
  if (!kg) {
    float* o = exO + qg * 2048;
    float m2 = exS[qg * 128 + lane];
    float l2 = exS[qg * 128 + 64 + lane];
    float m = fmaxf(m_run, m2);
    float f0 = fexp2(m_run - m), f2 = fexp2(m2 - m);
    l_run = l_run * f0 + l2 * f2;
#pragma unroll
    for (int r = 0; r < 16; r++) {
      oa0[r] = oa0[r] * f0 + o[r * 64 + lane] * f2;
      oa1[r] = oa1[r] * f0 + o[(16 + r) * 64 + lane] * f2;
    }
    // epilogue: oaX[r] = O[q=qrow][d = X*32 + (r&3) + 8*(r>>2) + 4*hi], / l
    int n = nh >> 3, h = nh & 7;
    float lf = 1.0f / l_run;
    u16* orow = Obf + ((size_t)n * S + qrow) * C + h * DH;
#pragma unroll
    for (int rq = 0; rq < 4; rq++) {
      int d0 = rq * 8 + 4 * hi;
      uint2 w0, w1;
      w0.x = cvtpk(oa0[rq * 4 + 0] * lf, oa0[rq * 4 + 1] * lf);
      w0.y = cvtpk(oa0[rq * 4 + 2] * lf, oa0[rq * 4 + 3] * lf);
      w1.x = cvtpk(oa1[rq * 4 + 0] * lf, oa1[rq * 4 + 1] * lf);
      w1.y = cvtpk(oa1[rq * 4 + 2] * lf, oa1[rq * 4 + 3] * lf);
      *(uint2*)(orow + d0) = w0;
      *(uint2*)(orow + 32 + d0) = w1;
    }
  }
}

}  // namespace

extern "C" void kernel_launch(void* const* d_in, const int* in_sizes, int n_in,
                              void* d_out, int out_size, void* d_ws, size_t ws_size,
                              hipStream_t stream) {
  const float* x       = (const float*)d_in[0];
  const float* qx      = (const float*)d_in[1];
  const float* q_ln_g  = (const float*)d_in[2];
  const float* q_ln_b  = (const float*)d_in[3];
  const float* q_w     = (const float*)d_in[4];
  const float* q_b     = (const float*)d_in[5];
  const float* kv_ln_g = (const float*)d_in[6];
  const float* kv_ln_b = (const float*)d_in[7];
  const float* kv_w    = (const float*)d_in[8];
  const float* kv_b    = (const float*)d_in[9];
  const float* proj_w  = (const float*)d_in[10];
  const float* proj_b  = (const float*)d_in[11];
  float* out = (float*)d_out;

  u16* u = (u16*)d_ws;
  u16* Xkv  = u;                u += (size_t)RTOT * C;
  u16* Xq   = u;                u += (size_t)RTOT * C;
  u16* Wtq  = u;                u += (size_t)C * C;
  u16* Wtkv = u;                u += (size_t)2 * C * C;
  u16* Wph  = u;                u += (size_t)C * C;
  u16* Qb   = u;                u += (size_t)NBATCH * HEADS * S * DH;
  u16* Kb   = u;                u += (size_t)NBATCH * HEADS * S * DH;
  u16* Vt   = u;                u += (size_t)NBATCH * HEADS * S * DH;
  u16* Obf  = u;

  hipLaunchKernelGGL(ln_fused, dim3(S / 32, 2 * NBATCH), dim3(256), 0, stream,
                     x, qx, kv_ln_g, kv_ln_b, q_ln_g, q_ln_b, Xkv, Xq);
  hipLaunchKernelGGL(prep_w, dim3(8, 16, 3), dim3(256), 0, stream,
                     q_w, kv_w, proj_w, Wtq, Wtkv, Wph);
  hipLaunchKernelGGL(gemm_qkv, dim3(12, RTOT / 128), dim3(256), 0, stream,
                     Xq, Xkv, Wtq, Wtkv, q_b, kv_b, Qb, Kb, Vt);
  hipLaunchKernelGGL(attn_kernel, dim3(1024), dim3(256), 0, stream,
                     Qb, Kb, Vt, Obf);
  hipLaunchKernelGGL(gemm_proj, dim3(C / 64, RTOT / 128), dim3(256), 0, stream,
                     Obf, Wph, proj_b, out);
}

// Round 12
// 87.064 us; speedup vs baseline: 1.3960x; 1.0121x over previous
//
#include <hip/hip_runtime.h>
#include <math.h>

namespace {

constexpr int S = 1024;
constexpr int C = 512;
constexpr int NBATCH = 8;
constexpr int RTOT = NBATCH * S;  // 8192
constexpr int HEADS = 8;
constexpr int DH = 64;

typedef __attribute__((ext_vector_type(8))) short bf16x8;
typedef __attribute__((ext_vector_type(4))) float f32x4;
typedef __attribute__((ext_vector_type(16))) float f32x16;
typedef unsigned short u16;
typedef unsigned int u32;

__device__ __forceinline__ u16 f2bf(float x) {
  union { float f; u32 u; } v; v.f = x;
  u32 r = v.u + 0x7FFF + ((v.u >> 16) & 1);
  return (u16)(r >> 16);
}
__device__ __forceinline__ float bf2f(u16 b) {
  union { u32 u; float f; } v; v.u = (u32)b << 16; return v.f;
}
__device__ __forceinline__ u32 cvtpk(float a, float b) {  // lo=a, hi=b (RTNE)
  u32 r;
  asm("v_cvt_pk_bf16_f32 %0, %1, %2" : "=v"(r) : "v"(a), "v"(b));
  return r;
}
__device__ __forceinline__ float fexp2(float x) {  // raw v_exp_f32 (2^x)
  float r;
  asm("v_exp_f32 %0, %1" : "=v"(r) : "v"(x));
  return r;
}
__device__ __forceinline__ float fmax3(float a, float b, float c) {
  return fmaxf(fmaxf(a, b), c);   // fuses to v_max3_f32
}
__device__ __forceinline__ void gl_lds16(const void* g, void* l) {
  auto gp = (const __attribute__((address_space(1))) u32*)g;
  auto lp = (__attribute__((address_space(3))) u32*)l;
  __builtin_amdgcn_global_load_lds(gp, lp, 16, 0, 0);
}

// ---------------- Fused LN: stats + apply + NCHW->(row,c) transpose + bf16 --
__global__ void ln_fused(const float* __restrict__ x, const float* __restrict__ qx,
                         const float* __restrict__ gx, const float* __restrict__ bx,
                         const float* __restrict__ gq, const float* __restrict__ bq,
                         u16* __restrict__ Xkv, u16* __restrict__ Xq) {
  __shared__ float Ssum[8][32], Ssq[8][32];
  __shared__ float mu_s[32], rs_s[32];
  __shared__ float T[2][32][65];
  int t = threadIdx.x;
  int si0 = blockIdx.x * 32;
  int isq = blockIdx.y & 1, n = blockIdx.y >> 1;
  const float* in = isq ? qx : x;
  const float* g  = isq ? gq : gx;
  const float* be = isq ? bq : bx;
  u16* out = isq ? Xq : Xkv;

  {
    int sl = t & 31, cg = t >> 5;
    const float* p = in + ((size_t)n * C + cg * 64) * S + si0 + sl;
    float s = 0.f, sq = 0.f;
#pragma unroll 8
    for (int c = 0; c < 64; c++) { float v = p[(size_t)c * S]; s += v; sq += v * v; }
    Ssum[cg][sl] = s; Ssq[cg][sl] = sq;
  }
  __syncthreads();
  if (t < 32) {
    float ss = 0.f, q2 = 0.f;
#pragma unroll
    for (int i = 0; i < 8; i++) { ss += Ssum[i][t]; q2 += Ssq[i][t]; }
    float m = ss * (1.0f / C);
    float var = q2 * (1.0f / C) - m * m;
    mu_s[t] = m; rs_s[t] = rsqrtf(var + 1e-5f);
  }
  __syncthreads();

  int si4 = (t & 7) * 4, cl = t >> 3;
  float4 mu4 = *(const float4*)&mu_s[si4];
  float4 rs4 = *(const float4*)&rs_s[si4];
  int wsl = t >> 3, wc8 = (t & 7) * 8;

  for (int it = 0; it < 8; it++) {   // c0 = it*64; ping-pong buffer
    int c0 = it * 64, b = it & 1;
#pragma unroll
    for (int i = 0; i < 2; i++) {
      int c = c0 + cl + i * 32;
      float4 v = *(const float4*)&in[((size_t)n * C + c) * S + si0 + si4];
      float gg = g[c], bb = be[c];
      T[b][si4 + 0][cl + i * 32] = (v.x - mu4.x) * rs4.x * gg + bb;
      T[b][si4 + 1][cl + i * 32] = (v.y - mu4.y) * rs4.y * gg + bb;
      T[b][si4 + 2][cl + i * 32] = (v.z - mu4.z) * rs4.z * gg + bb;
      T[b][si4 + 3][cl + i * 32] = (v.w - mu4.w) * rs4.w * gg + bb;
    }
    __syncthreads();
    u16 pk[8];
#pragma unroll
    for (int j = 0; j < 8; j++) pk[j] = f2bf(T[b][wsl][wc8 + j]);
    *(uint4*)&out[((size_t)(n * S + si0 + wsl)) * C + c0 + wc8] = *(const uint4*)pk;
  }
}

// ---------------- Weight prep: W[k][col] -> Wt[col][k] bf16 -----------------
__global__ void prep_w(const float* __restrict__ qw, const float* __restrict__ kvw,
                       const float* __restrict__ pw,
                       u16* __restrict__ Wtq, u16* __restrict__ Wtkv,
                       u16* __restrict__ Wph) {
  int z = blockIdx.z;
  int N = (z == 1) ? 1024 : 512;
  int col0 = blockIdx.y * 64;
  if (col0 >= N) return;
  int k0 = blockIdx.x * 64;
  const float* W = (z == 0) ? qw : (z == 1) ? kvw : pw;
  __shared__ float T[64][65];
  int t = threadIdx.x;
  int kl = t >> 4, c4 = (t & 15) * 4;
#pragma unroll
  for (int i = 0; i < 4; i++) {
    float4 v = *(const float4*)&W[(size_t)(k0 + kl + i * 16) * N + col0 + c4];
    T[kl + i * 16][c4 + 0] = v.x; T[kl + i * 16][c4 + 1] = v.y;
    T[kl + i * 16][c4 + 2] = v.z; T[kl + i * 16][c4 + 3] = v.w;
  }
  __syncthreads();
#pragma unroll
  for (int p = 0; p < 2; p++) {
    int cl = (t >> 3) + p * 32, k8 = (t & 7) * 8;
    u16 hi[8];
#pragma unroll
    for (int j = 0; j < 8; j++) hi[j] = f2bf(T[k8 + j][cl]);
    size_t o = (size_t)(col0 + cl) * 512 + k0 + k8;
    if (z == 0) *(uint4*)&Wtq[o] = *(const uint4*)hi;
    else if (z == 1) *(uint4*)&Wtkv[o] = *(const uint4*)hi;
    else *(uint4*)&Wph[o] = *(const uint4*)hi;
  }
}

// ---------------- MFMA GEMM: merged q+kv projection, 128x128 tile -----------
__global__ __launch_bounds__(256, 4) void gemm_qkv(
    const u16* __restrict__ Xq, const u16* __restrict__ Xkv,
    const u16* __restrict__ Wtq, const u16* __restrict__ Wtkv,
    const float* __restrict__ q_b, const float* __restrict__ kv_b,
    u16* __restrict__ Qb, u16* __restrict__ Kb, u16* __restrict__ Vt) {
  __shared__ __attribute__((aligned(16))) u16 As[128 * 64];
  __shared__ __attribute__((aligned(16))) u16 Bs[128 * 64];
  int t = threadIdx.x, wid = t >> 6, lane = t & 63, lr = lane & 15, lg = lane >> 4;
  int colb = blockIdx.x;
  const u16* A; const u16* Wt; const float* bias; int ch0;
  if (colb < 4) { A = Xq;  Wt = Wtq  + (size_t)colb * 128 * 512;       bias = q_b  + colb * 128;       ch0 = colb * 128; }
  else          { A = Xkv; Wt = Wtkv + (size_t)(colb - 4) * 128 * 512; bias = kv_b + (colb - 4) * 128; ch0 = 512 + (colb - 4) * 128; }
  int row0 = blockIdx.y * 128;
  int wr = wid >> 1, wc = wid & 1;
  f32x4 acc[4][4];
#pragma unroll
  for (int m = 0; m < 4; m++)
#pragma unroll
    for (int n = 0; n < 4; n++) acc[m][n] = (f32x4){0.f, 0.f, 0.f, 0.f};

  for (int k0 = 0; k0 < 512; k0 += 64) {
    __syncthreads();
#pragma unroll
    for (int it = 0; it < 4; it++) {
      int chunk = (wid * 4 + it) * 64 + lane;
      int r = chunk >> 3, sg = chunk & 7;
      gl_lds16(A + (size_t)(row0 + r) * 512 + k0 + ((sg ^ (r & 7)) * 8),
               (char*)As + (size_t)chunk * 16);
    }
#pragma unroll
    for (int it = 0; it < 4; it++) {
      int chunk = (wid * 4 + it) * 64 + lane;
      int r = chunk >> 3, sg = chunk & 7;
      gl_lds16(Wt + (size_t)r * 512 + k0 + ((sg ^ (r & 7)) * 8),
               (char*)Bs + (size_t)chunk * 16);
    }
    __syncthreads();
#pragma unroll
    for (int kk = 0; kk < 2; kk++) {
      bf16x8 bfr[4];
#pragma unroll
      for (int n = 0; n < 4; n++) {
        int col = wc * 64 + n * 16 + lr;
        bfr[n] = *(const bf16x8*)((const char*)Bs + col * 128 + (((kk * 4 + lg) ^ (col & 7)) << 4));
      }
#pragma unroll
      for (int m = 0; m < 4; m++) {
        int row = wr * 64 + m * 16 + lr;
        bf16x8 af = *(const bf16x8*)((const char*)As + row * 128 + (((kk * 4 + lg) ^ (row & 7)) << 4));
#pragma unroll
        for (int n = 0; n < 4; n++)
          acc[m][n] = __builtin_amdgcn_mfma_f32_16x16x32_bf16(af, bfr[n], acc[m][n], 0, 0, 0);
      }
    }
  }
#pragma unroll
  for (int m = 0; m < 4; m++)
#pragma unroll
    for (int n = 0; n < 4; n++) {
      int colg = wc * 64 + n * 16 + lr;
      int ch = ch0 + colg;
      int h = ch / 192, role = (ch >> 6) % 3, d = ch & 63;
      float bs = bias[colg];
      float qsc = (role == 0) ? 0.18033688f : 1.0f;  // 0.125 * log2(e)
      int growb = row0 + wr * 64 + m * 16 + lg * 4;
      int nn = growb >> 10, ssi0 = growb & (S - 1);
      size_t nh = (size_t)(nn * HEADS + h);
      if (role == 2) {
        u16 pk[4];
#pragma unroll
        for (int r = 0; r < 4; r++) pk[r] = f2bf(acc[m][n][r] + bs);
        *(uint2*)&Vt[(nh * DH + d) * S + ssi0] = *(const uint2*)pk;
      } else {
        u16* dst = (role == 0) ? Qb : Kb;
#pragma unroll
        for (int r = 0; r < 4; r++)
          dst[(nh * S + ssi0 + r) * DH + d] = f2bf((acc[m][n][r] + bs) * qsc);
      }
    }
}

// ---------------- MFMA GEMM: proj (Obf bf16 -> out NCHW), single bf16 W -----
__global__ __launch_bounds__(256, 4) void gemm_proj(
    const u16* __restrict__ Aob, const u16* __restrict__ Wh,
    const float* __restrict__ bias, float* __restrict__ out) {
  __shared__ __attribute__((aligned(16))) u16 As[128 * 64];
  __shared__ __attribute__((aligned(16))) u16 Bh[64 * 64];
  int t = threadIdx.x, wid = t >> 6, lane = t & 63, lr = lane & 15, lg = lane >> 4;
  int ch0 = blockIdx.x * 64, row0 = blockIdx.y * 128;
  int wc = wid & 1, wr = wid >> 1;
  f32x4 acc[2][4];
#pragma unroll
  for (int m = 0; m < 2; m++)
#pragma unroll
    for (int n = 0; n < 4; n++) acc[m][n] = (f32x4){0.f, 0.f, 0.f, 0.f};

  for (int k0 = 0; k0 < 512; k0 += 64) {
    __syncthreads();
#pragma unroll
    for (int it = 0; it < 4; it++) {
      int idx = (wid * 4 + it) * 64 + lane;
      int r = idx >> 3, sg = idx & 7;
      gl_lds16(Aob + (size_t)(row0 + r) * 512 + k0 + ((sg ^ (r & 7)) * 8),
               (char*)As + (wid * 4 + it) * 1024);
    }
#pragma unroll
    for (int it = 0; it < 2; it++) {
      int idx = (wid * 2 + it) * 64 + lane;
      int r = idx >> 3, sg = idx & 7;
      gl_lds16(Wh + (size_t)(ch0 + r) * 512 + k0 + ((sg ^ (r & 7)) * 8),
               (char*)Bh + (wid * 2 + it) * 1024);
    }
    __syncthreads();
#pragma unroll
    for (int kk = 0; kk < 2; kk++) {
      bf16x8 ar[4];
#pragma unroll
      for (int n = 0; n < 4; n++) {
        int row = wr * 64 + n * 16 + lr;
        ar[n] = *(const bf16x8*)((const char*)As + row * 128 + (((kk * 4 + lg) ^ (row & 7)) << 4));
      }
#pragma unroll
      for (int m = 0; m < 2; m++) {
        int ch = wc * 32 + m * 16 + lr;
        bf16x8 bh = *(const bf16x8*)((const char*)Bh + ch * 128 + (((kk * 4 + lg) ^ (ch & 7)) << 4));
#pragma unroll
        for (int n = 0; n < 4; n++)
          acc[m][n] = __builtin_amdgcn_mfma_f32_16x16x32_bf16(bh, ar[n], acc[m][n], 0, 0, 0);
      }
    }
  }
#pragma unroll
  for (int m = 0; m < 2; m++)
#pragma unroll
    for (int n = 0; n < 4; n++) {
      int rowg = row0 + wr * 64 + n * 16 + lr;
      int nn = rowg >> 10, ssi = rowg & (S - 1);
#pragma unroll
      for (int r = 0; r < 4; r++) {
        int ch = ch0 + wc * 32 + m * 16 + lg * 4 + r;
        out[((size_t)nn * C + ch) * S + ssi] = acc[m][n][r] + bias[ch];
      }
    }
}

// ---------------- 32x32 MFMA flash attention, KV-split, in-register P -------
// r11 structure + l-via-ones-MFMA (kills sum tree + 1 shfl) + max3 tree.
// permlane32_swap semantics (HW-confirmed r7): vdst.hi-lanes <-> vsrc.lo-lanes.
constexpr int KVB = 64;

__global__ __launch_bounds__(256, 4) void attn_kernel(
    const u16* __restrict__ Qbf, const u16* __restrict__ Kbf,
    const u16* __restrict__ Vtb, u16* __restrict__ Obf) {
  __shared__ __attribute__((aligned(16))) u16 Ks[2][KVB * DH];   // [key][d] 8KB x2
  __shared__ __attribute__((aligned(16))) u16 Vs[2][DH * KVB];   // [d][key] 8KB x2

  int tid = threadIdx.x;
  int wave = tid >> 6, lane = tid & 63;
  int lq = lane & 31, hi = lane >> 5;
  int qg = wave & 1, kg = wave >> 1;
  int w = (blockIdx.x & 7) * 128 + (blockIdx.x >> 3);
  int qt = w & 15, nh = w >> 4;
  const u16* Qg = Qbf + (size_t)nh * S * DH;
  const u16* Kg = Kbf + (size_t)nh * S * DH;
  const u16* Vg = Vtb + (size_t)nh * DH * S;

  int qrow = qt * 64 + qg * 32 + lq;
  bf16x8 qf[4];
#pragma unroll
  for (int ks = 0; ks < 4; ks++)
    qf[ks] = *(const bf16x8*)(Qg + (size_t)qrow * DH + ks * 16 + hi * 8);

  bf16x8 ones;
#pragma unroll
  for (int i = 0; i < 8; i++) ones[i] = (short)0x3F80;   // bf16 1.0

  f32x16 oa0 = {}, oa1 = {}, lacc = {};
  float m_run = -1e30f;   // per-lane (q = lq), log2 domain; l lives in lacc[0]

  int e0i = tid, e1i = tid + 256;
  int r0 = e0i >> 3, sg0 = e0i & 7, r1 = e1i >> 3, sg1 = e1i & 7;
  char* kd0 = (char*)&Ks[0][0] + (e0i & ~63) * 16;
  char* kd1 = (char*)&Ks[0][0] + (e1i & ~63) * 16;
  char* vd0 = (char*)&Vs[0][0] + (e0i & ~63) * 16;
  char* vd1 = (char*)&Vs[0][0] + (e1i & ~63) * 16;

#define STAGE(kb, b)                                                             \
  do {                                                                           \
    gl_lds16(Kg + (size_t)((kb) * KVB + r0) * 64 + ((sg0 ^ (r0 & 7)) * 8),       \
             kd0 + (b) * (KVB * DH * 2));                                        \
    gl_lds16(Kg + (size_t)((kb) * KVB + r1) * 64 + ((sg1 ^ (r1 & 7)) * 8),       \
             kd1 + (b) * (KVB * DH * 2));                                        \
    gl_lds16(Vg + (size_t)r0 * S + (kb) * KVB + ((sg0 ^ (r0 & 7)) * 8),          \
             vd0 + (b) * (KVB * DH * 2));                                        \
    gl_lds16(Vg + (size_t)r1 * S + (kb) * KVB + ((sg1 ^ (r1 & 7)) * 8),          \
             vd1 + (b) * (KVB * DH * 2));                                        \
  } while (0)

  STAGE(0, 0);

  for (int kb = 0; kb < S / KVB; kb++) {
    int cur = kb & 1;
    __syncthreads();
    if (kb + 1 < S / KVB) STAGE(kb + 1, cur ^ 1);

    const char* Kc = (const char*)&Ks[cur][0];
    const char* Vc = (const char*)&Vs[cur][0];

    // QK^T swapped: sc = K(32key x 64d) . Q(64d x 32q); keys kg*32+[0,32)
    f32x16 sc = {};
#pragma unroll
    for (int ks = 0; ks < 4; ks++) {
      int sg = ks * 2 + hi;
      bf16x8 kf = *(const bf16x8*)(Kc + (kg * 32 + lq) * 128 + ((sg ^ (lq & 7)) << 4));
      sc = __builtin_amdgcn_mfma_f32_32x32x16_bf16(kf, qf[ks], sc, 0, 0, 0);
    }

    // V frags hoisted (independent of softmax)
    bf16x8 vfr[2][2];
#pragma unroll
    for (int kk = 0; kk < 2; kk++) {
      int sg = kg * 4 + kk * 2 + hi;
      vfr[kk][0] = *(const bf16x8*)(Vc + lq * 128 + ((sg ^ (lq & 7)) << 4));
      vfr[kk][1] = *(const bf16x8*)(Vc + (32 + lq) * 128 + ((sg ^ (lq & 7)) << 4));
    }

    // max3 tree over 16 regs, then partner lane
    float g0 = fmax3(sc[0], sc[1], sc[2]);
    float g1 = fmax3(sc[3], sc[4], sc[5]);
    float g2 = fmax3(sc[6], sc[7], sc[8]);
    float g3 = fmax3(sc[9], sc[10], sc[11]);
    float g4 = fmax3(sc[12], sc[13], sc[14]);
    float pmax = fmax3(fmax3(g0, g1, g2), fmaxf(g3, g4), sc[15]);
    pmax = fmaxf(pmax, __shfl_xor(pmax, 32));

    // defer-max: 11.5 log2-units = 8 nats
    if (!__all(pmax <= m_run + 11.5f)) {
      float mnew = fmaxf(m_run, pmax);
      float corr = fexp2(m_run - mnew);
      m_run = mnew;
      lacc[0] *= corr;
#pragma unroll
      for (int r = 0; r < 16; r++) { oa0[r] *= corr; oa1[r] *= corr; }
    }

    // exp2 (raw v_exp_f32, in place); row-sum comes from the ones-MFMA below
#pragma unroll
    for (int r = 0; r < 16; r++) sc[r] = fexp2(sc[r] - m_run);

    // pack P to bf16 pairs and exchange halves in-register
    u32 c[8];
    c[0] = cvtpk(sc[0],  sc[1]);  c[1] = cvtpk(sc[2],  sc[3]);
    c[2] = cvtpk(sc[4],  sc[5]);  c[3] = cvtpk(sc[6],  sc[7]);
    c[4] = cvtpk(sc[8],  sc[9]);  c[5] = cvtpk(sc[10], sc[11]);
    c[6] = cvtpk(sc[12], sc[13]); c[7] = cvtpk(sc[14], sc[15]);
    asm("v_permlane32_swap_b32 %0, %1" : "+v"(c[0]), "+v"(c[2]));
    asm("v_permlane32_swap_b32 %0, %1" : "+v"(c[1]), "+v"(c[3]));
    asm("v_permlane32_swap_b32 %0, %1" : "+v"(c[4]), "+v"(c[6]));
    asm("v_permlane32_swap_b32 %0, %1" : "+v"(c[5]), "+v"(c[7]));

    // PV swapped: O += Vt . P;  l += ones . P (row-sum on the MFMA pipe)
#pragma unroll
    for (int kk = 0; kk < 2; kk++) {
      union { u32 u[4]; bf16x8 v; } pu;
      pu.u[0] = c[kk * 4 + 0]; pu.u[1] = c[kk * 4 + 1];
      pu.u[2] = c[kk * 4 + 2]; pu.u[3] = c[kk * 4 + 3];
      lacc = __builtin_amdgcn_mfma_f32_32x32x16_bf16(ones, pu.v, lacc, 0, 0, 0);
      oa0 = __builtin_amdgcn_mfma_f32_32x32x16_bf16(vfr[kk][0], pu.v, oa0, 0, 0, 0);
      oa1 = __builtin_amdgcn_mfma_f32_32x32x16_bf16(vfr[kk][1], pu.v, oa1, 0, 0, 0);
    }
  }
#undef STAGE

  float l_run = lacc[0];
  // merge kg=1 partials into kg=0 (layout [reg][lane] -> conflict-free)
  __syncthreads();
  float* exO = (float*)&Ks[0][0];   // 2 slots x 32 regs x 64 lanes = 16KB
  float* exS = (float*)&Vs[0][0];
  if (kg) {
    float* o = exO + qg * 2048;
#pragma unroll
    for (int r = 0; r < 16; r++) {
      o[r * 64 + lane] = oa0[r];
      o[(16 + r) * 64 + lane] = oa1[r];
    }
    exS[qg * 128 + lane] = m_run;
    exS[qg * 128 + 64 + lane] = l_run;
  }
  __syncthreads();
  if (!kg) {
    float* o = exO + qg * 2048;
    float m2 = exS[qg * 128 + lane];
    float l2 = exS[qg * 128 + 64 + lane];
    float m = fmaxf(m_run, m2);
    float f0 = fexp2(m_run - m), f2 = fexp2(m2 - m);
    l_run = l_run * f0 + l2 * f2;
#pragma unroll
    for (int r = 0; r < 16; r++) {
      oa0[r] = oa0[r] * f0 + o[r * 64 + lane] * f2;
      oa1[r] = oa1[r] * f0 + o[(16 + r) * 64 + lane] * f2;
    }
    // epilogue: oaX[r] = O[q=qrow][d = X*32 + (r&3) + 8*(r>>2) + 4*hi], / l
    int n = nh >> 3, h = nh & 7;
    float lf = 1.0f / l_run;
    u16* orow = Obf + ((size_t)n * S + qrow) * C + h * DH;
#pragma unroll
    for (int rq = 0; rq < 4; rq++) {
      int d0 = rq * 8 + 4 * hi;
      uint2 w0, w1;
      w0.x = cvtpk(oa0[rq * 4 + 0] * lf, oa0[rq * 4 + 1] * lf);
      w0.y = cvtpk(oa0[rq * 4 + 2] * lf, oa0[rq * 4 + 3] * lf);
      w1.x = cvtpk(oa1[rq * 4 + 0] * lf, oa1[rq * 4 + 1] * lf);
      w1.y = cvtpk(oa1[rq * 4 + 2] * lf, oa1[rq * 4 + 3] * lf);
      *(uint2*)(orow + d0) = w0;
      *(uint2*)(orow + 32 + d0) = w1;
    }
  }
}

}  // namespace

extern "C" void kernel_launch(void* const* d_in, const int* in_sizes, int n_in,
                              void* d_out, int out_size, void* d_ws, size_t ws_size,
                              hipStream_t stream) {
  const float* x       = (const float*)d_in[0];
  const float* qx      = (const float*)d_in[1];
  const float* q_ln_g  = (const float*)d_in[2];
  const float* q_ln_b  = (const float*)d_in[3];
  const float* q_w     = (const float*)d_in[4];
  const float* q_b     = (const float*)d_in[5];
  const float* kv_ln_g = (const float*)d_in[6];
  const float* kv_ln_b = (const float*)d_in[7];
  const float* kv_w    = (const float*)d_in[8];
  const float* kv_b    = (const float*)d_in[9];
  const float* proj_w  = (const float*)d_in[10];
  const float* proj_b  = (const float*)d_in[11];
  float* out = (float*)d_out;

  u16* u = (u16*)d_ws;
  u16* Xkv  = u;                u += (size_t)RTOT * C;
  u16* Xq   = u;                u += (size_t)RTOT * C;
  u16* Wtq  = u;                u += (size_t)C * C;
  u16* Wtkv = u;                u += (size_t)2 * C * C;
  u16* Wph  = u;                u += (size_t)C * C;
  u16* Qb   = u;                u += (size_t)NBATCH * HEADS * S * DH;
  u16* Kb   = u;                u += (size_t)NBATCH * HEADS * S * DH;
  u16* Vt   = u;                u += (size_t)NBATCH * HEADS * S * DH;
  u16* Obf  = u;

  hipLaunchKernelGGL(ln_fused, dim3(S / 32, 2 * NBATCH), dim3(256), 0, stream,
                     x, qx, kv_ln_g, kv_ln_b, q_ln_g, q_ln_b, Xkv, Xq);
  hipLaunchKernelGGL(prep_w, dim3(8, 16, 3), dim3(256), 0, stream,
                     q_w, kv_w, proj_w, Wtq, Wtkv, Wph);
  hipLaunchKernelGGL(gemm_qkv, dim3(12, RTOT / 128), dim3(256), 0, stream,
                     Xq, Xkv, Wtq, Wtkv, q_b, kv_b, Qb, Kb, Vt);
  hipLaunchKernelGGL(attn_kernel, dim3(1024), dim3(256), 0, stream,
                     Qb, Kb, Vt, Obf);
  hipLaunchKernelGGL(gemm_proj, dim3(C / 64, RTOT / 128), dim3(256), 0, stream,
                     Obf, Wph, proj_b, out);
}

// Round 13
// 80.743 us; speedup vs baseline: 1.5052x; 1.0783x over previous
//
#include <hip/hip_runtime.h>
#include <math.h>

namespace {

constexpr int S = 1024;
constexpr int C = 512;
constexpr int NBATCH = 8;
constexpr int RTOT = NBATCH * S;  // 8192
constexpr int HEADS = 8;
constexpr int DH = 64;

typedef __attribute__((ext_vector_type(8))) short bf16x8;
typedef __attribute__((ext_vector_type(4))) float f32x4;
typedef __attribute__((ext_vector_type(16))) float f32x16;
typedef unsigned short u16;
typedef unsigned int u32;

__device__ __forceinline__ u16 f2bf(float x) {
  union { float f; u32 u; } v; v.f = x;
  u32 r = v.u + 0x7FFF + ((v.u >> 16) & 1);
  return (u16)(r >> 16);
}
__device__ __forceinline__ float bf2f(u16 b) {
  union { u32 u; float f; } v; v.u = (u32)b << 16; return v.f;
}
__device__ __forceinline__ u32 cvtpk(float a, float b) {  // lo=a, hi=b (RTNE)
  u32 r;
  asm("v_cvt_pk_bf16_f32 %0, %1, %2" : "=v"(r) : "v"(a), "v"(b));
  return r;
}
__device__ __forceinline__ float fexp2(float x) {  // raw v_exp_f32 (2^x)
  float r;
  asm("v_exp_f32 %0, %1" : "=v"(r) : "v"(x));
  return r;
}
__device__ __forceinline__ float fmax3(float a, float b, float c) {
  return fmaxf(fmaxf(a, b), c);   // fuses to v_max3_f32
}
__device__ __forceinline__ void gl_lds16(const void* g, void* l) {
  auto gp = (const __attribute__((address_space(1))) u32*)g;
  auto lp = (__attribute__((address_space(3))) u32*)l;
  __builtin_amdgcn_global_load_lds(gp, lp, 16, 0, 0);
}

// ---------------- Merged: LN (blocks 0..511) + weight prep (512..767) -------
__global__ void ln_prep(const float* __restrict__ x, const float* __restrict__ qx,
                        const float* __restrict__ gx, const float* __restrict__ bx,
                        const float* __restrict__ gq, const float* __restrict__ bq,
                        u16* __restrict__ Xkv, u16* __restrict__ Xq,
                        const float* __restrict__ qw, const float* __restrict__ kvw,
                        const float* __restrict__ pw,
                        u16* __restrict__ Wtq, u16* __restrict__ Wtkv,
                        u16* __restrict__ Wph) {
  __shared__ __attribute__((aligned(16))) float smemf[4736];
  int bid = blockIdx.x;
  int t = threadIdx.x;

  if (bid < 512) {
    // ---------------- LN path ----------------
    float (*Ssum)[32] = (float(*)[32])smemf;
    float (*Ssq)[32]  = (float(*)[32])(smemf + 256);
    float* mu_s = smemf + 512;
    float* rs_s = smemf + 544;
    float (*T)[32][65] = (float(*)[32][65])(smemf + 576);

    int si0 = (bid & 31) * 32;
    int yy = bid >> 5;
    int isq = yy & 1, n = yy >> 1;
    const float* in = isq ? qx : x;
    const float* g  = isq ? gq : gx;
    const float* be = isq ? bq : bx;
    u16* out = isq ? Xq : Xkv;

    {
      int sl = t & 31, cg = t >> 5;
      const float* p = in + ((size_t)n * C + cg * 64) * S + si0 + sl;
      float s = 0.f, sq = 0.f;
#pragma unroll 8
      for (int c = 0; c < 64; c++) { float v = p[(size_t)c * S]; s += v; sq += v * v; }
      Ssum[cg][sl] = s; Ssq[cg][sl] = sq;
    }
    __syncthreads();
    if (t < 32) {
      float ss = 0.f, q2 = 0.f;
#pragma unroll
      for (int i = 0; i < 8; i++) { ss += Ssum[i][t]; q2 += Ssq[i][t]; }
      float m = ss * (1.0f / C);
      float var = q2 * (1.0f / C) - m * m;
      mu_s[t] = m; rs_s[t] = rsqrtf(var + 1e-5f);
    }
    __syncthreads();

    int si4 = (t & 7) * 4, cl = t >> 3;
    float4 mu4 = *(const float4*)&mu_s[si4];
    float4 rs4 = *(const float4*)&rs_s[si4];
    int wsl = t >> 3, wc8 = (t & 7) * 8;

    for (int it = 0; it < 8; it++) {   // c0 = it*64; ping-pong buffer
      int c0 = it * 64, b = it & 1;
#pragma unroll
      for (int i = 0; i < 2; i++) {
        int c = c0 + cl + i * 32;
        float4 v = *(const float4*)&in[((size_t)n * C + c) * S + si0 + si4];
        float gg = g[c], bb = be[c];
        T[b][si4 + 0][cl + i * 32] = (v.x - mu4.x) * rs4.x * gg + bb;
        T[b][si4 + 1][cl + i * 32] = (v.y - mu4.y) * rs4.y * gg + bb;
        T[b][si4 + 2][cl + i * 32] = (v.z - mu4.z) * rs4.z * gg + bb;
        T[b][si4 + 3][cl + i * 32] = (v.w - mu4.w) * rs4.w * gg + bb;
      }
      __syncthreads();
      u16 pk[8];
#pragma unroll
      for (int j = 0; j < 8; j++) pk[j] = f2bf(T[b][wsl][wc8 + j]);
      *(uint4*)&out[((size_t)(n * S + si0 + wsl)) * C + c0 + wc8] = *(const uint4*)pk;
    }
  } else {
    // ---------------- weight-prep path ----------------
    float (*T)[65] = (float(*)[65])smemf;
    int pid = bid - 512;
    int z, k0t, colt;
    if (pid < 64)       { z = 0;               k0t = pid & 7; colt = pid >> 3; }
    else if (pid < 192) { z = 1; pid -= 64;    k0t = pid & 7; colt = pid >> 3; }
    else                { z = 2; pid -= 192;   k0t = pid & 7; colt = pid >> 3; }
    int N = (z == 1) ? 1024 : 512;
    int col0 = colt * 64, k0 = k0t * 64;
    const float* W = (z == 0) ? qw : (z == 1) ? kvw : pw;

    int kl = t >> 4, c4 = (t & 15) * 4;
#pragma unroll
    for (int i = 0; i < 4; i++) {
      float4 v = *(const float4*)&W[(size_t)(k0 + kl + i * 16) * N + col0 + c4];
      T[kl + i * 16][c4 + 0] = v.x; T[kl + i * 16][c4 + 1] = v.y;
      T[kl + i * 16][c4 + 2] = v.z; T[kl + i * 16][c4 + 3] = v.w;
    }
    __syncthreads();
#pragma unroll
    for (int p = 0; p < 2; p++) {
      int cl = (t >> 3) + p * 32, k8 = (t & 7) * 8;
      u16 hi[8];
#pragma unroll
      for (int j = 0; j < 8; j++) hi[j] = f2bf(T[k8 + j][cl]);
      size_t o = (size_t)(col0 + cl) * 512 + k0 + k8;
      if (z == 0) *(uint4*)&Wtq[o] = *(const uint4*)hi;
      else if (z == 1) *(uint4*)&Wtkv[o] = *(const uint4*)hi;
      else *(uint4*)&Wph[o] = *(const uint4*)hi;
    }
  }
}

// ---------------- MFMA GEMM: merged q+kv projection, 128x128 tile -----------
// grid 768 (flat); XCD-chunked swizzle: each XCD gets 8 row-panels x 12 colb
__global__ __launch_bounds__(256, 4) void gemm_qkv(
    const u16* __restrict__ Xq, const u16* __restrict__ Xkv,
    const u16* __restrict__ Wtq, const u16* __restrict__ Wtkv,
    const float* __restrict__ q_b, const float* __restrict__ kv_b,
    u16* __restrict__ Qb, u16* __restrict__ Kb, u16* __restrict__ Vt) {
  __shared__ __attribute__((aligned(16))) u16 As[128 * 64];
  __shared__ __attribute__((aligned(16))) u16 Bs[128 * 64];
  int t = threadIdx.x, wid = t >> 6, lane = t & 63, lr = lane & 15, lg = lane >> 4;
  int bid = blockIdx.x;
  int wg = (bid & 7) * 96 + (bid >> 3);   // 768 = 8 XCD x 96, bijective
  int colb = wg % 12;
  int row0 = (wg / 12) * 128;
  const u16* A; const u16* Wt; const float* bias; int ch0;
  if (colb < 4) { A = Xq;  Wt = Wtq  + (size_t)colb * 128 * 512;       bias = q_b  + colb * 128;       ch0 = colb * 128; }
  else          { A = Xkv; Wt = Wtkv + (size_t)(colb - 4) * 128 * 512; bias = kv_b + (colb - 4) * 128; ch0 = 512 + (colb - 4) * 128; }
  int wr = wid >> 1, wc = wid & 1;
  f32x4 acc[4][4];
#pragma unroll
  for (int m = 0; m < 4; m++)
#pragma unroll
    for (int n = 0; n < 4; n++) acc[m][n] = (f32x4){0.f, 0.f, 0.f, 0.f};

  for (int k0 = 0; k0 < 512; k0 += 64) {
    __syncthreads();
#pragma unroll
    for (int it = 0; it < 4; it++) {
      int chunk = (wid * 4 + it) * 64 + lane;
      int r = chunk >> 3, sg = chunk & 7;
      gl_lds16(A + (size_t)(row0 + r) * 512 + k0 + ((sg ^ (r & 7)) * 8),
               (char*)As + (size_t)chunk * 16);
    }
#pragma unroll
    for (int it = 0; it < 4; it++) {
      int chunk = (wid * 4 + it) * 64 + lane;
      int r = chunk >> 3, sg = chunk & 7;
      gl_lds16(Wt + (size_t)r * 512 + k0 + ((sg ^ (r & 7)) * 8),
               (char*)Bs + (size_t)chunk * 16);
    }
    __syncthreads();
#pragma unroll
    for (int kk = 0; kk < 2; kk++) {
      bf16x8 bfr[4];
#pragma unroll
      for (int n = 0; n < 4; n++) {
        int col = wc * 64 + n * 16 + lr;
        bfr[n] = *(const bf16x8*)((const char*)Bs + col * 128 + (((kk * 4 + lg) ^ (col & 7)) << 4));
      }
#pragma unroll
      for (int m = 0; m < 4; m++) {
        int row = wr * 64 + m * 16 + lr;
        bf16x8 af = *(const bf16x8*)((const char*)As + row * 128 + (((kk * 4 + lg) ^ (row & 7)) << 4));
#pragma unroll
        for (int n = 0; n < 4; n++)
          acc[m][n] = __builtin_amdgcn_mfma_f32_16x16x32_bf16(af, bfr[n], acc[m][n], 0, 0, 0);
      }
    }
  }
#pragma unroll
  for (int m = 0; m < 4; m++)
#pragma unroll
    for (int n = 0; n < 4; n++) {
      int colg = wc * 64 + n * 16 + lr;
      int ch = ch0 + colg;
      int h = ch / 192, role = (ch >> 6) % 3, d = ch & 63;
      float bs = bias[colg];
      float qsc = (role == 0) ? 0.18033688f : 1.0f;  // 0.125 * log2(e)
      int growb = row0 + wr * 64 + m * 16 + lg * 4;
      int nn = growb >> 10, ssi0 = growb & (S - 1);
      size_t nh = (size_t)(nn * HEADS + h);
      if (role == 2) {
        u16 pk[4];
#pragma unroll
        for (int r = 0; r < 4; r++) pk[r] = f2bf(acc[m][n][r] + bs);
        *(uint2*)&Vt[(nh * DH + d) * S + ssi0] = *(const uint2*)pk;
      } else {
        u16* dst = (role == 0) ? Qb : Kb;
#pragma unroll
        for (int r = 0; r < 4; r++)
          dst[(nh * S + ssi0 + r) * DH + d] = f2bf((acc[m][n][r] + bs) * qsc);
      }
    }
}

// ---------------- MFMA GEMM: proj (Obf bf16 -> out NCHW), single bf16 W -----
// grid 512 (flat); XCD-chunked swizzle: each XCD gets 8 row-panels x 8 chb
__global__ __launch_bounds__(256, 4) void gemm_proj(
    const u16* __restrict__ Aob, const u16* __restrict__ Wh,
    const float* __restrict__ bias, float* __restrict__ out) {
  __shared__ __attribute__((aligned(16))) u16 As[128 * 64];
  __shared__ __attribute__((aligned(16))) u16 Bh[64 * 64];
  int t = threadIdx.x, wid = t >> 6, lane = t & 63, lr = lane & 15, lg = lane >> 4;
  int bid = blockIdx.x;
  int wg = (bid & 7) * 64 + (bid >> 3);   // 512 = 8 XCD x 64, bijective
  int ch0 = (wg % 8) * 64;
  int row0 = (wg / 8) * 128;
  int wc = wid & 1, wr = wid >> 1;
  f32x4 acc[2][4];
#pragma unroll
  for (int m = 0; m < 2; m++)
#pragma unroll
    for (int n = 0; n < 4; n++) acc[m][n] = (f32x4){0.f, 0.f, 0.f, 0.f};

  for (int k0 = 0; k0 < 512; k0 += 64) {
    __syncthreads();
#pragma unroll
    for (int it = 0; it < 4; it++) {
      int idx = (wid * 4 + it) * 64 + lane;
      int r = idx >> 3, sg = idx & 7;
      gl_lds16(Aob + (size_t)(row0 + r) * 512 + k0 + ((sg ^ (r & 7)) * 8),
               (char*)As + (wid * 4 + it) * 1024);
    }
#pragma unroll
    for (int it = 0; it < 2; it++) {
      int idx = (wid * 2 + it) * 64 + lane;
      int r = idx >> 3, sg = idx & 7;
      gl_lds16(Wh + (size_t)(ch0 + r) * 512 + k0 + ((sg ^ (r & 7)) * 8),
               (char*)Bh + (wid * 2 + it) * 1024);
    }
    __syncthreads();
#pragma unroll
    for (int kk = 0; kk < 2; kk++) {
      bf16x8 ar[4];
#pragma unroll
      for (int n = 0; n < 4; n++) {
        int row = wr * 64 + n * 16 + lr;
        ar[n] = *(const bf16x8*)((const char*)As + row * 128 + (((kk * 4 + lg) ^ (row & 7)) << 4));
      }
#pragma unroll
      for (int m = 0; m < 2; m++) {
        int ch = wc * 32 + m * 16 + lr;
        bf16x8 bh = *(const bf16x8*)((const char*)Bh + ch * 128 + (((kk * 4 + lg) ^ (ch & 7)) << 4));
#pragma unroll
        for (int n = 0; n < 4; n++)
          acc[m][n] = __builtin_amdgcn_mfma_f32_16x16x32_bf16(bh, ar[n], acc[m][n], 0, 0, 0);
      }
    }
  }
#pragma unroll
  for (int m = 0; m < 2; m++)
#pragma unroll
    for (int n = 0; n < 4; n++) {
      int rowg = row0 + wr * 64 + n * 16 + lr;
      int nn = rowg >> 10, ssi = rowg & (S - 1);
#pragma unroll
      for (int r = 0; r < 4; r++) {
        int ch = ch0 + wc * 32 + m * 16 + lg * 4 + r;
        out[((size_t)nn * C + ch) * S + ssi] = acc[m][n][r] + bias[ch];
      }
    }
}

// ---------------- 32x32 MFMA flash attention, KV-split, in-register P -------
// r12 structure (unchanged).
constexpr int KVB = 64;

__global__ __launch_bounds__(256, 4) void attn_kernel(
    const u16* __restrict__ Qbf, const u16* __restrict__ Kbf,
    const u16* __restrict__ Vtb, u16* __restrict__ Obf) {
  __shared__ __attribute__((aligned(16))) u16 Ks[2][KVB * DH];   // [key][d] 8KB x2
  __shared__ __attribute__((aligned(16))) u16 Vs[2][DH * KVB];   // [d][key] 8KB x2

  int tid = threadIdx.x;
  int wave = tid >> 6, lane = tid & 63;
  int lq = lane & 31, hi = lane >> 5;
  int qg = wave & 1, kg = wave >> 1;
  int w = (blockIdx.x & 7) * 128 + (blockIdx.x >> 3);
  int qt = w & 15, nh = w >> 4;
  const u16* Qg = Qbf + (size_t)nh * S * DH;
  const u16* Kg = Kbf + (size_t)nh * S * DH;
  const u16* Vg = Vtb + (size_t)nh * DH * S;

  int qrow = qt * 64 + qg * 32 + lq;
  bf16x8 qf[4];
#pragma unroll
  for (int ks = 0; ks < 4; ks++)
    qf[ks] = *(const bf16x8*)(Qg + (size_t)qrow * DH + ks * 16 + hi * 8);

  bf16x8 ones;
#pragma unroll
  for (int i = 0; i < 8; i++) ones[i] = (short)0x3F80;   // bf16 1.0

  f32x16 oa0 = {}, oa1 = {}, lacc = {};
  float m_run = -1e30f;   // per-lane (q = lq), log2 domain; l lives in lacc[0]

  int e0i = tid, e1i = tid + 256;
  int r0 = e0i >> 3, sg0 = e0i & 7, r1 = e1i >> 3, sg1 = e1i & 7;
  char* kd0 = (char*)&Ks[0][0] + (e0i & ~63) * 16;
  char* kd1 = (char*)&Ks[0][0] + (e1i & ~63) * 16;
  char* vd0 = (char*)&Vs[0][0] + (e0i & ~63) * 16;
  char* vd1 = (char*)&Vs[0][0] + (e1i & ~63) * 16;

#define STAGE(kb, b)                                                             \
  do {                                                                           \
    gl_lds16(Kg + (size_t)((kb) * KVB + r0) * 64 + ((sg0 ^ (r0 & 7)) * 8),       \
             kd0 + (b) * (KVB * DH * 2));                                        \
    gl_lds16(Kg + (size_t)((kb) * KVB + r1) * 64 + ((sg1 ^ (r1 & 7)) * 8),       \
             kd1 + (b) * (KVB * DH * 2));                                        \
    gl_lds16(Vg + (size_t)r0 * S + (kb) * KVB + ((sg0 ^ (r0 & 7)) * 8),          \
             vd0 + (b) * (KVB * DH * 2));                                        \
    gl_lds16(Vg + (size_t)r1 * S + (kb) * KVB + ((sg1 ^ (r1 & 7)) * 8),          \
             vd1 + (b) * (KVB * DH * 2));                                        \
  } while (0)

  STAGE(0, 0);

  for (int kb = 0; kb < S / KVB; kb++) {
    int cur = kb & 1;
    __syncthreads();
    if (kb + 1 < S / KVB) STAGE(kb + 1, cur ^ 1);

    const char* Kc = (const char*)&Ks[cur][0];
    const char* Vc = (const char*)&Vs[cur][0];

    // QK^T swapped: sc = K(32key x 64d) . Q(64d x 32q); keys kg*32+[0,32)
    f32x16 sc = {};
#pragma unroll
    for (int ks = 0; ks < 4; ks++) {
      int sg = ks * 2 + hi;
      bf16x8 kf = *(const bf16x8*)(Kc + (kg * 32 + lq) * 128 + ((sg ^ (lq & 7)) << 4));
      sc = __builtin_amdgcn_mfma_f32_32x32x16_bf16(kf, qf[ks], sc, 0, 0, 0);
    }

    // V frags hoisted (independent of softmax)
    bf16x8 vfr[2][2];
#pragma unroll
    for (int kk = 0; kk < 2; kk++) {
      int sg = kg * 4 + kk * 2 + hi;
      vfr[kk][0] = *(const bf16x8*)(Vc + lq * 128 + ((sg ^ (lq & 7)) << 4));
      vfr[kk][1] = *(const bf16x8*)(Vc + (32 + lq) * 128 + ((sg ^ (lq & 7)) << 4));
    }

    // max3 tree over 16 regs, then partner lane
    float g0 = fmax3(sc[0], sc[1], sc[2]);
    float g1 = fmax3(sc[3], sc[4], sc[5]);
    float g2 = fmax3(sc[6], sc[7], sc[8]);
    float g3 = fmax3(sc[9], sc[10], sc[11]);
    float g4 = fmax3(sc[12], sc[13], sc[14]);
    float pmax = fmax3(fmax3(g0, g1, g2), fmaxf(g3, g4), sc[15]);
    pmax = fmaxf(pmax, __shfl_xor(pmax, 32));

    // defer-max: 11.5 log2-units = 8 nats
    if (!__all(pmax <= m_run + 11.5f)) {
      float mnew = fmaxf(m_run, pmax);
      float corr = fexp2(m_run - mnew);
      m_run = mnew;
      lacc[0] *= corr;
#pragma unroll
      for (int r = 0; r < 16; r++) { oa0[r] *= corr; oa1[r] *= corr; }
    }

    // exp2 (raw v_exp_f32, in place); row-sum comes from the ones-MFMA below
#pragma unroll
    for (int r = 0; r < 16; r++) sc[r] = fexp2(sc[r] - m_run);

    // pack P to bf16 pairs and exchange halves in-register
    u32 c[8];
    c[0] = cvtpk(sc[0],  sc[1]);  c[1] = cvtpk(sc[2],  sc[3]);
    c[2] = cvtpk(sc[4],  sc[5]);  c[3] = cvtpk(sc[6],  sc[7]);
    c[4] = cvtpk(sc[8],  sc[9]);  c[5] = cvtpk(sc[10], sc[11]);
    c[6] = cvtpk(sc[12], sc[13]); c[7] = cvtpk(sc[14], sc[15]);
    asm("v_permlane32_swap_b32 %0, %1" : "+v"(c[0]), "+v"(c[2]));
    asm("v_permlane32_swap_b32 %0, %1" : "+v"(c[1]), "+v"(c[3]));
    asm("v_permlane32_swap_b32 %0, %1" : "+v"(c[4]), "+v"(c[6]));
    asm("v_permlane32_swap_b32 %0, %1" : "+v"(c[5]), "+v"(c[7]));

    // PV swapped: O += Vt . P;  l += ones . P (row-sum on the MFMA pipe)
#pragma unroll
    for (int kk = 0; kk < 2; kk++) {
      union { u32 u[4]; bf16x8 v; } pu;
      pu.u[0] = c[kk * 4 + 0]; pu.u[1] = c[kk * 4 + 1];
      pu.u[2] = c[kk * 4 + 2]; pu.u[3] = c[kk * 4 + 3];
      lacc = __builtin_amdgcn_mfma_f32_32x32x16_bf16(ones, pu.v, lacc, 0, 0, 0);
      oa0 = __builtin_amdgcn_mfma_f32_32x32x16_bf16(vfr[kk][0], pu.v, oa0, 0, 0, 0);
      oa1 = __builtin_amdgcn_mfma_f32_32x32x16_bf16(vfr[kk][1], pu.v, oa1, 0, 0, 0);
    }
  }
#undef STAGE

  float l_run = lacc[0];
  // merge kg=1 partials into kg=0 (layout [reg][lane] -> conflict-free)
  __syncthreads();
  float* exO = (float*)&Ks[0][0];   // 2 slots x 32 regs x 64 lanes = 16KB
  float* exS = (float*)&Vs[0][0];
  if (kg) {
    float* o = exO + qg * 2048;
#pragma unroll
    for (int r = 0; r < 16; r++) {
      o[r * 64 + lane] = oa0[r];
      o[(16 + r) * 64 + lane] = oa1[r];
    }
    exS[qg * 128 + lane] = m_run;
    exS[qg * 128 + 64 + lane] = l_run;
  }
  __syncthreads();
  if (!kg) {
    float* o = exO + qg * 2048;
    float m2 = exS[qg * 128 + lane];
    float l2 = exS[qg * 128 + 64 + lane];
    float m = fmaxf(m_run, m2);
    float f0 = fexp2(m_run - m), f2 = fexp2(m2 - m);
    l_run = l_run * f0 + l2 * f2;
#pragma unroll
    for (int r = 0; r < 16; r++) {
      oa0[r] = oa0[r] * f0 + o[r * 64 + lane] * f2;
      oa1[r] = oa1[r] * f0 + o[(16 + r) * 64 + lane] * f2;
    }
    // epilogue: oaX[r] = O[q=qrow][d = X*32 + (r&3) + 8*(r>>2) + 4*hi], / l
    int n = nh >> 3, h = nh & 7;
    float lf = 1.0f / l_run;
    u16* orow = Obf + ((size_t)n * S + qrow) * C + h * DH;
#pragma unroll
    for (int rq = 0; rq < 4; rq++) {
      int d0 = rq * 8 + 4 * hi;
      uint2 w0, w1;
      w0.x = cvtpk(oa0[rq * 4 + 0] * lf, oa0[rq * 4 + 1] * lf);
      w0.y = cvtpk(oa0[rq * 4 + 2] * lf, oa0[rq * 4 + 3] * lf);
      w1.x = cvtpk(oa1[rq * 4 + 0] * lf, oa1[rq * 4 + 1] * lf);
      w1.y = cvtpk(oa1[rq * 4 + 2] * lf, oa1[rq * 4 + 3] * lf);
      *(uint2*)(orow + d0) = w0;
      *(uint2*)(orow + 32 + d0) = w1;
    }
  }
}

}  // namespace

extern "C" void kernel_launch(void* const* d_in, const int* in_sizes, int n_in,
                              void* d_out, int out_size, void* d_ws, size_t ws_size,
                              hipStream_t stream) {
  const float* x       = (const float*)d_in[0];
  const float* qx      = (const float*)d_in[1];
  const float* q_ln_g  = (const float*)d_in[2];
  const float* q_ln_b  = (const float*)d_in[3];
  const float* q_w     = (const float*)d_in[4];
  const float* q_b     = (const float*)d_in[5];
  const float* kv_ln_g = (const float*)d_in[6];
  const float* kv_ln_b = (const float*)d_in[7];
  const float* kv_w    = (const float*)d_in[8];
  const float* kv_b    = (const float*)d_in[9];
  const float* proj_w  = (const float*)d_in[10];
  const float* proj_b  = (const float*)d_in[11];
  float* out = (float*)d_out;

  u16* u = (u16*)d_ws;
  u16* Xkv  = u;                u += (size_t)RTOT * C;
  u16* Xq   = u;                u += (size_t)RTOT * C;
  u16* Wtq  = u;                u += (size_t)C * C;
  u16* Wtkv = u;                u += (size_t)2 * C * C;
  u16* Wph  = u;                u += (size_t)C * C;
  u16* Qb   = u;                u += (size_t)NBATCH * HEADS * S * DH;
  u16* Kb   = u;                u += (size_t)NBATCH * HEADS * S * DH;
  u16* Vt   = u;                u += (size_t)NBATCH * HEADS * S * DH;
  u16* Obf  = u;

  hipLaunchKernelGGL(ln_prep, dim3(768), dim3(256), 0, stream,
                     x, qx, kv_ln_g, kv_ln_b, q_ln_g, q_ln_b, Xkv, Xq,
                     q_w, kv_w, proj_w, Wtq, Wtkv, Wph);
  hipLaunchKernelGGL(gemm_qkv, dim3(768), dim3(256), 0, stream,
                     Xq, Xkv, Wtq, Wtkv, q_b, kv_b, Qb, Kb, Vt);
  hipLaunchKernelGGL(attn_kernel, dim3(1024), dim3(256), 0, stream,
                     Qb, Kb, Vt, Obf);
  hipLaunchKernelGGL(gemm_proj, dim3(512), dim3(256), 0, stream,
                     Obf, Wph, proj_b, out);
}